// Round 1
// baseline (7137.273 us; speedup 1.0000x reference)
//
#include <hip/hip_runtime.h>
#include <hip/hip_bf16.h>
#include <cstddef>

#define V_N 30000
#define E_N 480000
#define HID 256
#define HEADS 4
#define HD 64
#define M_ROWS 1024   // 2*512
#define K_DIM 30000
#define NEG_SLOPE 0.2f
#define EPS_F 1e-9f

// ---------------- Phase 1: H[src[e],:] += val[e] * W[dst[e],:] ----------------
// one wave per edge; lane handles 4 floats (float4 load of W row)
__global__ __launch_bounds__(256) void k_scatter_H(
    const int* __restrict__ src, const int* __restrict__ dst,
    const float* __restrict__ val, const float* __restrict__ W,
    float* __restrict__ H) {
  int e = blockIdx.x * 4 + (threadIdx.x >> 6);
  if (e >= E_N) return;
  int lane = threadIdx.x & 63;
  int s = src[e], d = dst[e];
  float v = val[e];
  float4 w = reinterpret_cast<const float4*>(W + (size_t)d * HID)[lane];
  float* hr = H + (size_t)s * HID + lane * 4;
  unsafeAtomicAdd(hr + 0, v * w.x);
  unsafeAtomicAdd(hr + 1, v * w.y);
  unsafeAtomicAdd(hr + 2, v * w.z);
  unsafeAtomicAdd(hr + 3, v * w.w);
}

// ---------------- Phase 2: per-vertex attention partial scores ----------------
// block = vertex (256 threads = 4 heads x 64 dims); wave-reduce per head
__global__ __launch_bounds__(256) void k_scores(
    const float* __restrict__ H, const float* __restrict__ a,
    float* __restrict__ s0, float* __restrict__ s1) {
  int v = blockIdx.x;
  int t = threadIdx.x;
  int h = t >> 6, d = t & 63;
  float hv = H[(size_t)v * HID + t];
  float e0 = hv * a[h * (2 * HD) + d];
  float e1 = hv * a[h * (2 * HD) + HD + d];
  #pragma unroll
  for (int off = 32; off > 0; off >>= 1) {
    e0 += __shfl_down(e0, off);
    e1 += __shfl_down(e1, off);
  }
  if (d == 0) {
    s0[v * HEADS + h] = e0;
    s1[v * HEADS + h] = e1;
  }
}

// ---------------- Phase 3: edge scores -> exp, denom scatter ----------------
__global__ __launch_bounds__(256) void k_edge(
    const int* __restrict__ src, const int* __restrict__ dst,
    const float* __restrict__ s0, const float* __restrict__ s1,
    float* __restrict__ eexp, float* __restrict__ denom) {
  int i = blockIdx.x * 256 + threadIdx.x;
  if (i >= E_N * HEADS) return;
  int e = i >> 2, h = i & 3;
  int sv = src[e], dv = dst[e];
  float sc = s0[sv * HEADS + h] + s1[dv * HEADS + h];
  sc = sc > 0.f ? sc : NEG_SLOPE * sc;
  float ex = expf(sc);
  eexp[i] = ex;
  unsafeAtomicAdd(&denom[dv * HEADS + h], ex);
}

// ---------------- Phase 4: Hsum[dst[e]] += alpha * H[src[e]] ----------------
__global__ __launch_bounds__(256) void k_agg(
    const int* __restrict__ src, const int* __restrict__ dst,
    const float* __restrict__ eexp, const float* __restrict__ denom,
    const float* __restrict__ H, float* __restrict__ Hsum) {
  int e = blockIdx.x * 4 + (threadIdx.x >> 6);
  if (e >= E_N) return;
  int lane = threadIdx.x & 63;
  int h = lane >> 4;          // 4 floats/lane -> head = lane/16
  int sv = src[e], dv = dst[e];
  float alpha = eexp[e * HEADS + h] / (denom[dv * HEADS + h] + EPS_F);
  float4 hv = reinterpret_cast<const float4*>(H + (size_t)sv * HID)[lane];
  float* o = Hsum + (size_t)dv * HID + lane * 4;
  unsafeAtomicAdd(o + 0, alpha * hv.x);
  unsafeAtomicAdd(o + 1, alpha * hv.y);
  unsafeAtomicAdd(o + 2, alpha * hv.z);
  unsafeAtomicAdd(o + 3, alpha * hv.w);
}

// ---------------- Phase 5: fused = X @ Hsum  (fp32 tiled, split-K) ----------------
#define BM 64
#define BN 64
#define BK 16
__global__ __launch_bounds__(256) void k_gemm1(
    const float* __restrict__ X, const float* __restrict__ Hs,
    float* __restrict__ fused) {
  __shared__ float As[BM][BK + 1];
  __shared__ float Bs[BK][BN];
  const int t = threadIdx.x;
  const int bm = blockIdx.x, bn = blockIdx.y;
  const int SK = gridDim.z;
  const int chunk = (K_DIM + SK - 1) / SK;
  const int k0 = blockIdx.z * chunk;
  const int kend = min(k0 + chunk, K_DIM);
  const int tx = t & 15, ty = t >> 4;   // A loads
  const int bx = t & 63, by = t >> 6;   // B loads
  const int tn = t & 15, tm = t >> 4;   // compute mapping
  const int row0 = bm * BM, col0 = bn * BN;
  float acc[4][4] = {};
  for (int kb = k0; kb < kend; kb += BK) {
    #pragma unroll
    for (int p = 0; p < 4; ++p) {
      int r = ty + p * 16;
      int kk = kb + tx;
      As[r][tx] = (kk < kend) ? X[(size_t)(row0 + r) * K_DIM + kk] : 0.f;
    }
    #pragma unroll
    for (int p = 0; p < 4; ++p) {
      int kk = kb + by + p * 4;
      Bs[by + p * 4][bx] = (kk < kend) ? Hs[(size_t)kk * HID + col0 + bx] : 0.f;
    }
    __syncthreads();
    #pragma unroll
    for (int k = 0; k < BK; ++k) {
      float ar[4], br[4];
      #pragma unroll
      for (int i = 0; i < 4; ++i) ar[i] = As[tm * 4 + i][k];
      #pragma unroll
      for (int j = 0; j < 4; ++j) br[j] = Bs[k][tn * 4 + j];
      #pragma unroll
      for (int i = 0; i < 4; ++i)
        #pragma unroll
        for (int j = 0; j < 4; ++j)
          acc[i][j] += ar[i] * br[j];
    }
    __syncthreads();
  }
  #pragma unroll
  for (int i = 0; i < 4; ++i)
    #pragma unroll
    for (int j = 0; j < 4; ++j)
      unsafeAtomicAdd(&fused[(size_t)(row0 + tm * 4 + i) * HID + col0 + tn * 4 + j],
                      acc[i][j]);
}

// ---------------- Phase 6: out = fused @ fc_w^T + fc_b ----------------
__global__ __launch_bounds__(256) void k_gemm2(
    const float* __restrict__ fused, const float* __restrict__ fc_w,
    const float* __restrict__ fc_b, float* __restrict__ out) {
  int bd = blockIdx.x, o = threadIdx.x;
  __shared__ float fs[HID];
  fs[o] = fused[(size_t)bd * HID + o];
  __syncthreads();
  float acc = fc_b[o];
  const float* wr = fc_w + (size_t)o * HID;
  #pragma unroll 8
  for (int h = 0; h < HID; ++h) acc += fs[h] * wr[h];
  out[(size_t)bd * HID + o] = acc;
}

extern "C" void kernel_launch(void* const* d_in, const int* in_sizes, int n_in,
                              void* d_out, int out_size, void* d_ws, size_t ws_size,
                              hipStream_t stream) {
  const float* X    = (const float*)d_in[0];
  const float* W0   = (const float*)d_in[1];
  const float* a0   = (const float*)d_in[2];
  const float* W1   = (const float*)d_in[3];
  const float* a1   = (const float*)d_in[4];
  const float* fc_w = (const float*)d_in[5];
  const float* fc_b = (const float*)d_in[6];
  const float* val0 = (const float*)d_in[7];
  const float* val1 = (const float*)d_in[8];
  const int*   src0 = (const int*)d_in[9];
  const int*   dst0 = (const int*)d_in[10];
  const int*   src1 = (const int*)d_in[11];
  const int*   dst1 = (const int*)d_in[12];
  float* out = (float*)d_out;

  char* ws = (char*)d_ws;
  size_t off = 0;
  auto alloc = [&](size_t bytes) {
    void* p = ws + off;
    off += (bytes + 255) & ~(size_t)255;
    return p;
  };
  float* H     = (float*)alloc((size_t)V_N * HID * 4);
  float* Hsum  = (float*)alloc((size_t)V_N * HID * 4);
  float* s0    = (float*)alloc((size_t)V_N * HEADS * 4);
  float* s1    = (float*)alloc((size_t)V_N * HEADS * 4);
  float* denom = (float*)alloc((size_t)V_N * HEADS * 4);
  float* eexp  = (float*)alloc((size_t)E_N * HEADS * 4);
  float* fused = (float*)alloc((size_t)M_ROWS * HID * 4);

  hipMemsetAsync(Hsum, 0, (size_t)V_N * HID * 4, stream);
  hipMemsetAsync(fused, 0, (size_t)M_ROWS * HID * 4, stream);

  for (int g = 0; g < 2; ++g) {
    const float* W   = g ? W1 : W0;
    const float* a   = g ? a1 : a0;
    const float* val = g ? val1 : val0;
    const int* src   = g ? src1 : src0;
    const int* dst   = g ? dst1 : dst0;

    hipMemsetAsync(H, 0, (size_t)V_N * HID * 4, stream);
    hipMemsetAsync(denom, 0, (size_t)V_N * HEADS * 4, stream);

    k_scatter_H<<<E_N / 4, 256, 0, stream>>>(src, dst, val, W, H);
    k_scores<<<V_N, 256, 0, stream>>>(H, a, s0, s1);
    k_edge<<<(E_N * HEADS) / 256, 256, 0, stream>>>(src, dst, s0, s1, eexp, denom);
    k_agg<<<E_N / 4, 256, 0, stream>>>(src, dst, eexp, denom, H, Hsum);
  }

  k_gemm1<<<dim3(M_ROWS / BM, HID / BN, 8), 256, 0, stream>>>(X, Hsum, fused);
  k_gemm2<<<M_ROWS, 256, 0, stream>>>(fused, fc_w, fc_b, out);
}

// Round 2
// 1313.435 us; speedup vs baseline: 5.4340x; 5.4340x over previous
//
#include <hip/hip_runtime.h>
#include <hip/hip_bf16.h>
#include <cstddef>

#define V_N 30000
#define E_N 480000
#define HID 256
#define HEADS 4
#define HD 64
#define M_ROWS 1024   // 2*512
#define K_DIM 30000
#define NEG_SLOPE 0.2f
#define EPS_F 1e-9f

// ---------- CSR build: histogram ----------
__global__ __launch_bounds__(256) void k_hist(
    const int* __restrict__ s0g, const int* __restrict__ d0g,
    const int* __restrict__ s1g, const int* __restrict__ d1g,
    int* __restrict__ deg) {  // 4 arrays of V_N: [g0src, g0dst, g1src, g1dst]
  int e = blockIdx.x * 256 + threadIdx.x;
  if (e >= E_N) return;
  atomicAdd(&deg[0 * V_N + s0g[e]], 1);
  atomicAdd(&deg[1 * V_N + d0g[e]], 1);
  atomicAdd(&deg[2 * V_N + s1g[e]], 1);
  atomicAdd(&deg[3 * V_N + d1g[e]], 1);
}

// ---------- CSR build: 4 independent exclusive scans (blockIdx = which array) ----------
__global__ __launch_bounds__(1024) void k_scan4(
    const int* __restrict__ deg, int* __restrict__ rowptrs, int* __restrict__ cursors) {
  const int* dg = deg + blockIdx.x * V_N;
  int* rp = rowptrs + blockIdx.x * (V_N + 1);
  int* cur = cursors + blockIdx.x * V_N;
  __shared__ int part[1024];
  const int t = threadIdx.x;
  const int C = (V_N + 1023) / 1024;  // 30
  int base = t * C;
  int loc[C];
  int s = 0;
  #pragma unroll
  for (int i = 0; i < C; ++i) {
    int idx = base + i;
    int d = (idx < V_N) ? dg[idx] : 0;
    loc[i] = s;
    s += d;
  }
  part[t] = s;
  __syncthreads();
  for (int off = 1; off < 1024; off <<= 1) {
    int v_ = (t >= off) ? part[t - off] : 0;
    __syncthreads();
    part[t] += v_;
    __syncthreads();
  }
  int pre = (t == 0) ? 0 : part[t - 1];
  #pragma unroll
  for (int i = 0; i < C; ++i) {
    int idx = base + i;
    if (idx < V_N) {
      int v_ = pre + loc[i];
      rp[idx] = v_;
      cur[idx] = v_;
    }
  }
  if (t == 1023) rp[V_N] = part[1023];
}

// ---------- CSR build: fill edge indices ----------
__global__ __launch_bounds__(256) void k_fill(
    const int* __restrict__ s0g, const int* __restrict__ d0g,
    const int* __restrict__ s1g, const int* __restrict__ d1g,
    int* __restrict__ cursors, int* __restrict__ eidx) {
  int e = blockIdx.x * 256 + threadIdx.x;
  if (e >= E_N) return;
  int p;
  p = atomicAdd(&cursors[0 * V_N + s0g[e]], 1); eidx[0 * (size_t)E_N + p] = e;
  p = atomicAdd(&cursors[1 * V_N + d0g[e]], 1); eidx[1 * (size_t)E_N + p] = e;
  p = atomicAdd(&cursors[2 * V_N + s1g[e]], 1); eidx[2 * (size_t)E_N + p] = e;
  p = atomicAdd(&cursors[3 * V_N + d1g[e]], 1); eidx[3 * (size_t)E_N + p] = e;
}

// ---------- Phase 1+2: H[v] = sum val*W[dst] over src-bucket; fused score precompute ----------
// one wave per vertex, lane owns 4 contiguous floats of the 256-wide row
__global__ __launch_bounds__(256) void k_gather_H(
    const int* __restrict__ rp, const int* __restrict__ eidx,
    const int* __restrict__ dst, const float* __restrict__ val,
    const float* __restrict__ W, const float* __restrict__ a,
    float* __restrict__ H, float* __restrict__ s0, float* __restrict__ s1) {
  int v = blockIdx.x * 4 + (threadIdx.x >> 6);
  if (v >= V_N) return;
  int lane = threadIdx.x & 63;
  int start = rp[v], end = rp[v + 1];
  const float4* W4 = reinterpret_cast<const float4*>(W);
  float4 acc = {0.f, 0.f, 0.f, 0.f};
  int d_nxt = 0; float f_nxt = 0.f;
  if (start < end) { int e = eidx[start]; d_nxt = dst[e]; f_nxt = val[e]; }
  for (int i = start; i < end; ++i) {
    int d = d_nxt; float f = f_nxt;
    if (i + 1 < end) { int e = eidx[i + 1]; d_nxt = dst[e]; f_nxt = val[e]; }
    float4 w = W4[(size_t)d * 64 + lane];
    acc.x += f * w.x; acc.y += f * w.y; acc.z += f * w.z; acc.w += f * w.w;
  }
  reinterpret_cast<float4*>(H)[(size_t)v * 64 + lane] = acc;
  // scores: head = lane>>4, dims (lane&15)*4 .. +3 within head
  int h = lane >> 4, dd = (lane & 15) * 4;
  const float* ah = a + h * (2 * HD);
  float p0 = acc.x * ah[dd] + acc.y * ah[dd + 1] + acc.z * ah[dd + 2] + acc.w * ah[dd + 3];
  float p1 = acc.x * ah[HD + dd] + acc.y * ah[HD + dd + 1] + acc.z * ah[HD + dd + 2] + acc.w * ah[HD + dd + 3];
  #pragma unroll
  for (int off = 1; off < 16; off <<= 1) {
    p0 += __shfl_xor(p0, off);
    p1 += __shfl_xor(p1, off);
  }
  if ((lane & 15) == 0) {
    s0[v * HEADS + h] = p0;
    s1[v * HEADS + h] = p1;
  }
}

// ---------- Phase 3+4: softmax denom + aggregation, dst-CSR, no atomics ----------
__global__ __launch_bounds__(256) void k_fused_agg(
    const int* __restrict__ rp, const int* __restrict__ eidx,
    const int* __restrict__ src, const float* __restrict__ s0,
    const float* __restrict__ s1, const float* __restrict__ H,
    float* __restrict__ Hsum) {
  int v = blockIdx.x * 4 + (threadIdx.x >> 6);
  if (v >= V_N) return;
  int lane = threadIdx.x & 63;
  int start = rp[v], end = rp[v + 1];
  // pass A: denominators. lane = idx*4 + h; 16 edges x 4 heads per iter
  int hA = lane & 3, idx = lane >> 2;
  float s1A = s1[v * HEADS + hA];
  float dsum = 0.f;
  for (int i0 = start; i0 < end; i0 += 16) {
    int i = i0 + idx;
    if (i < end) {
      int e = eidx[i];
      int sv = src[e];
      float sc = s0[sv * HEADS + hA] + s1A;
      sc = sc > 0.f ? sc : NEG_SLOPE * sc;
      dsum += expf(sc);
    }
  }
  #pragma unroll
  for (int off = 4; off < 64; off <<= 1) dsum += __shfl_xor(dsum, off);
  // pass B: lane owns 4 floats of output row; head = lane>>4
  int hB = lane >> 4;
  float denom = __shfl(dsum, hB) + EPS_F;  // lane j (j<4) holds head j's denom
  float s1B = s1[v * HEADS + hB];
  const float4* H4 = reinterpret_cast<const float4*>(H);
  float4 acc = {0.f, 0.f, 0.f, 0.f};
  int sv_nxt = 0;
  if (start < end) sv_nxt = src[eidx[start]];
  for (int i = start; i < end; ++i) {
    int sv = sv_nxt;
    if (i + 1 < end) sv_nxt = src[eidx[i + 1]];
    float sc = s0[sv * HEADS + hB] + s1B;
    sc = sc > 0.f ? sc : NEG_SLOPE * sc;
    float alpha = expf(sc) / denom;
    float4 hr = H4[(size_t)sv * 64 + lane];
    acc.x += alpha * hr.x; acc.y += alpha * hr.y;
    acc.z += alpha * hr.z; acc.w += alpha * hr.w;
  }
  float4* o = reinterpret_cast<float4*>(Hsum) + (size_t)v * 64 + lane;
  float4 prev = *o;
  prev.x += acc.x; prev.y += acc.y; prev.z += acc.z; prev.w += acc.w;
  *o = prev;
}

// ---------- Phase 5: fused = X @ Hsum (fp32 tiled, split-K) ----------
#define BM 64
#define BN 64
#define BK 16
__global__ __launch_bounds__(256) void k_gemm1(
    const float* __restrict__ X, const float* __restrict__ Hs,
    float* __restrict__ fused) {
  __shared__ float As[BM][BK + 1];
  __shared__ float Bs[BK][BN];
  const int t = threadIdx.x;
  const int bm = blockIdx.x, bn = blockIdx.y;
  const int SK = gridDim.z;
  const int chunk = (K_DIM + SK - 1) / SK;
  const int k0 = blockIdx.z * chunk;
  const int kend = min(k0 + chunk, K_DIM);
  const int tx = t & 15, ty = t >> 4;
  const int bx = t & 63, by = t >> 6;
  const int tn = t & 15, tm = t >> 4;
  const int row0 = bm * BM, col0 = bn * BN;
  float acc[4][4] = {};
  for (int kb = k0; kb < kend; kb += BK) {
    #pragma unroll
    for (int p = 0; p < 4; ++p) {
      int r = ty + p * 16;
      int kk = kb + tx;
      As[r][tx] = (kk < kend) ? X[(size_t)(row0 + r) * K_DIM + kk] : 0.f;
    }
    #pragma unroll
    for (int p = 0; p < 4; ++p) {
      int kk = kb + by + p * 4;
      Bs[by + p * 4][bx] = (kk < kend) ? Hs[(size_t)kk * HID + col0 + bx] : 0.f;
    }
    __syncthreads();
    #pragma unroll
    for (int k = 0; k < BK; ++k) {
      float ar[4], br[4];
      #pragma unroll
      for (int i = 0; i < 4; ++i) ar[i] = As[tm * 4 + i][k];
      #pragma unroll
      for (int j = 0; j < 4; ++j) br[j] = Bs[k][tn * 4 + j];
      #pragma unroll
      for (int i = 0; i < 4; ++i)
        #pragma unroll
        for (int j = 0; j < 4; ++j)
          acc[i][j] += ar[i] * br[j];
    }
    __syncthreads();
  }
  #pragma unroll
  for (int i = 0; i < 4; ++i)
    #pragma unroll
    for (int j = 0; j < 4; ++j)
      unsafeAtomicAdd(&fused[(size_t)(row0 + tm * 4 + i) * HID + col0 + tn * 4 + j],
                      acc[i][j]);
}

// ---------- Phase 6: out = fused @ fc_w^T + fc_b ----------
__global__ __launch_bounds__(256) void k_gemm2(
    const float* __restrict__ fused, const float* __restrict__ fc_w,
    const float* __restrict__ fc_b, float* __restrict__ out) {
  int bd = blockIdx.x, o = threadIdx.x;
  __shared__ float fs[HID];
  fs[o] = fused[(size_t)bd * HID + o];
  __syncthreads();
  float acc = fc_b[o];
  const float* wr = fc_w + (size_t)o * HID;
  #pragma unroll 8
  for (int h = 0; h < HID; ++h) acc += fs[h] * wr[h];
  out[(size_t)bd * HID + o] = acc;
}

extern "C" void kernel_launch(void* const* d_in, const int* in_sizes, int n_in,
                              void* d_out, int out_size, void* d_ws, size_t ws_size,
                              hipStream_t stream) {
  const float* X    = (const float*)d_in[0];
  const float* W0   = (const float*)d_in[1];
  const float* a0   = (const float*)d_in[2];
  const float* W1   = (const float*)d_in[3];
  const float* a1   = (const float*)d_in[4];
  const float* fc_w = (const float*)d_in[5];
  const float* fc_b = (const float*)d_in[6];
  const float* val0 = (const float*)d_in[7];
  const float* val1 = (const float*)d_in[8];
  const int*   src0 = (const int*)d_in[9];
  const int*   dst0 = (const int*)d_in[10];
  const int*   src1 = (const int*)d_in[11];
  const int*   dst1 = (const int*)d_in[12];
  float* out = (float*)d_out;

  char* ws = (char*)d_ws;
  size_t off = 0;
  auto alloc = [&](size_t bytes) {
    void* p = ws + off;
    off += (bytes + 255) & ~(size_t)255;
    return p;
  };
  int*   deg     = (int*)alloc(4 * (size_t)V_N * 4);
  int*   rowptrs = (int*)alloc(4 * (size_t)(V_N + 1) * 4);
  int*   cursors = (int*)alloc(4 * (size_t)V_N * 4);
  int*   eidx    = (int*)alloc(4 * (size_t)E_N * 4);
  float* H       = (float*)alloc((size_t)V_N * HID * 4);
  float* Hsum    = (float*)alloc((size_t)V_N * HID * 4);
  float* s0      = (float*)alloc((size_t)V_N * HEADS * 4);
  float* s1      = (float*)alloc((size_t)V_N * HEADS * 4);
  float* fused   = (float*)alloc((size_t)M_ROWS * HID * 4);

  hipMemsetAsync(deg, 0, 4 * (size_t)V_N * 4, stream);
  hipMemsetAsync(Hsum, 0, (size_t)V_N * HID * 4, stream);
  hipMemsetAsync(fused, 0, (size_t)M_ROWS * HID * 4, stream);

  const int EB = (E_N + 255) / 256;
  k_hist<<<EB, 256, 0, stream>>>(src0, dst0, src1, dst1, deg);
  k_scan4<<<4, 1024, 0, stream>>>(deg, rowptrs, cursors);
  k_fill<<<EB, 256, 0, stream>>>(src0, dst0, src1, dst1, cursors, eidx);

  const int VB = (V_N + 3) / 4;
  for (int g = 0; g < 2; ++g) {
    const float* W   = g ? W1 : W0;
    const float* a   = g ? a1 : a0;
    const float* val = g ? val1 : val0;
    const int* src   = g ? src1 : src0;
    const int* dst   = g ? dst1 : dst0;
    const int* rp_s  = rowptrs + (g * 2 + 0) * (V_N + 1);
    const int* rp_d  = rowptrs + (g * 2 + 1) * (V_N + 1);
    const int* ei_s  = eidx + (size_t)(g * 2 + 0) * E_N;
    const int* ei_d  = eidx + (size_t)(g * 2 + 1) * E_N;

    k_gather_H<<<VB, 256, 0, stream>>>(rp_s, ei_s, dst, val, W, a, H, s0, s1);
    k_fused_agg<<<VB, 256, 0, stream>>>(rp_d, ei_d, src, s0, s1, H, Hsum);
  }

  k_gemm1<<<dim3(M_ROWS / BM, HID / BN, 8), 256, 0, stream>>>(X, Hsum, fused);
  k_gemm2<<<M_ROWS, 256, 0, stream>>>(fused, fc_w, fc_b, out);
}

// Round 3
// 1000.283 us; speedup vs baseline: 7.1353x; 1.3131x over previous
//
#include <hip/hip_runtime.h>
#include <hip/hip_bf16.h>
#include <cstddef>

#define V_N 30000
#define E_N 480000
#define HID 256
#define HEADS 4
#define HD 64
#define M_ROWS 1024   // 2*512
#define K_DIM 30000
#define K_PAD 30080   // = 32*940, divisible by 64
#define SK_MFMA 20    // 940 K-steps / 20 = 47 steps per z-block
#define STEPS_Z 47
#define NEG_SLOPE 0.2f
#define EPS_F 1e-9f

typedef __attribute__((ext_vector_type(8))) short bf16x8;
typedef __attribute__((ext_vector_type(4))) float f32x4;
typedef __attribute__((ext_vector_type(8))) unsigned short u16x8;

__device__ inline unsigned short f2bf_rtn(float f) {
  unsigned u = __float_as_uint(f);
  unsigned r = u + 0x7fffu + ((u >> 16) & 1u);
  return (unsigned short)(r >> 16);
}
__device__ inline float bf2f(unsigned short h) {
  return __uint_as_float(((unsigned)h) << 16);
}

// ---------- CSR build: histogram ----------
__global__ __launch_bounds__(256) void k_hist(
    const int* __restrict__ s0g, const int* __restrict__ d0g,
    const int* __restrict__ s1g, const int* __restrict__ d1g,
    int* __restrict__ deg) {
  int e = blockIdx.x * 256 + threadIdx.x;
  if (e >= E_N) return;
  atomicAdd(&deg[0 * V_N + s0g[e]], 1);
  atomicAdd(&deg[1 * V_N + d0g[e]], 1);
  atomicAdd(&deg[2 * V_N + s1g[e]], 1);
  atomicAdd(&deg[3 * V_N + d1g[e]], 1);
}

// ---------- CSR build: 4 independent exclusive scans ----------
__global__ __launch_bounds__(1024) void k_scan4(
    const int* __restrict__ deg, int* __restrict__ rowptrs, int* __restrict__ cursors) {
  const int* dg = deg + blockIdx.x * V_N;
  int* rp = rowptrs + blockIdx.x * (V_N + 1);
  int* cur = cursors + blockIdx.x * V_N;
  __shared__ int part[1024];
  const int t = threadIdx.x;
  const int C = (V_N + 1023) / 1024;  // 30
  int base = t * C;
  int loc[C];
  int s = 0;
  #pragma unroll
  for (int i = 0; i < C; ++i) {
    int idx = base + i;
    int d = (idx < V_N) ? dg[idx] : 0;
    loc[i] = s;
    s += d;
  }
  part[t] = s;
  __syncthreads();
  for (int off = 1; off < 1024; off <<= 1) {
    int v_ = (t >= off) ? part[t - off] : 0;
    __syncthreads();
    part[t] += v_;
    __syncthreads();
  }
  int pre = (t == 0) ? 0 : part[t - 1];
  #pragma unroll
  for (int i = 0; i < C; ++i) {
    int idx = base + i;
    if (idx < V_N) {
      int v_ = pre + loc[i];
      rp[idx] = v_;
      cur[idx] = v_;
    }
  }
  if (t == 1023) rp[V_N] = part[1023];
}

// ---------- CSR build: fill edge indices ----------
__global__ __launch_bounds__(256) void k_fill(
    const int* __restrict__ s0g, const int* __restrict__ d0g,
    const int* __restrict__ s1g, const int* __restrict__ d1g,
    int* __restrict__ cursors, int* __restrict__ eidx) {
  int e = blockIdx.x * 256 + threadIdx.x;
  if (e >= E_N) return;
  int p;
  p = atomicAdd(&cursors[0 * V_N + s0g[e]], 1); eidx[0 * (size_t)E_N + p] = e;
  p = atomicAdd(&cursors[1 * V_N + d0g[e]], 1); eidx[1 * (size_t)E_N + p] = e;
  p = atomicAdd(&cursors[2 * V_N + s1g[e]], 1); eidx[2 * (size_t)E_N + p] = e;
  p = atomicAdd(&cursors[3 * V_N + d1g[e]], 1); eidx[3 * (size_t)E_N + p] = e;
}

// ---------- Phase 1+2: H gather + fused score precompute ----------
__global__ __launch_bounds__(256) void k_gather_H(
    const int* __restrict__ rp, const int* __restrict__ eidx,
    const int* __restrict__ dst, const float* __restrict__ val,
    const float* __restrict__ W, const float* __restrict__ a,
    float* __restrict__ H, float* __restrict__ s0, float* __restrict__ s1) {
  int v = blockIdx.x * 4 + (threadIdx.x >> 6);
  if (v >= V_N) return;
  int lane = threadIdx.x & 63;
  int start = rp[v], end = rp[v + 1];
  const float4* W4 = reinterpret_cast<const float4*>(W);
  float4 acc = {0.f, 0.f, 0.f, 0.f};
  int d_nxt = 0; float f_nxt = 0.f;
  if (start < end) { int e = eidx[start]; d_nxt = dst[e]; f_nxt = val[e]; }
  for (int i = start; i < end; ++i) {
    int d = d_nxt; float f = f_nxt;
    if (i + 1 < end) { int e = eidx[i + 1]; d_nxt = dst[e]; f_nxt = val[e]; }
    float4 w = W4[(size_t)d * 64 + lane];
    acc.x += f * w.x; acc.y += f * w.y; acc.z += f * w.z; acc.w += f * w.w;
  }
  reinterpret_cast<float4*>(H)[(size_t)v * 64 + lane] = acc;
  int h = lane >> 4, dd = (lane & 15) * 4;
  const float* ah = a + h * (2 * HD);
  float p0 = acc.x * ah[dd] + acc.y * ah[dd + 1] + acc.z * ah[dd + 2] + acc.w * ah[dd + 3];
  float p1 = acc.x * ah[HD + dd] + acc.y * ah[HD + dd + 1] + acc.z * ah[HD + dd + 2] + acc.w * ah[HD + dd + 3];
  #pragma unroll
  for (int off = 1; off < 16; off <<= 1) {
    p0 += __shfl_xor(p0, off);
    p1 += __shfl_xor(p1, off);
  }
  if ((lane & 15) == 0) {
    s0[v * HEADS + h] = p0;
    s1[v * HEADS + h] = p1;
  }
}

// ---------- Phase 3+4: softmax denom + aggregation ----------
__global__ __launch_bounds__(256) void k_fused_agg(
    const int* __restrict__ rp, const int* __restrict__ eidx,
    const int* __restrict__ src, const float* __restrict__ s0,
    const float* __restrict__ s1, const float* __restrict__ H,
    float* __restrict__ Hsum) {
  int v = blockIdx.x * 4 + (threadIdx.x >> 6);
  if (v >= V_N) return;
  int lane = threadIdx.x & 63;
  int start = rp[v], end = rp[v + 1];
  int hA = lane & 3, idx = lane >> 2;
  float s1A = s1[v * HEADS + hA];
  float dsum = 0.f;
  for (int i0 = start; i0 < end; i0 += 16) {
    int i = i0 + idx;
    if (i < end) {
      int e = eidx[i];
      int sv = src[e];
      float sc = s0[sv * HEADS + hA] + s1A;
      sc = sc > 0.f ? sc : NEG_SLOPE * sc;
      dsum += expf(sc);
    }
  }
  #pragma unroll
  for (int off = 4; off < 64; off <<= 1) dsum += __shfl_xor(dsum, off);
  int hB = lane >> 4;
  float denom = __shfl(dsum, hB) + EPS_F;
  float s1B = s1[v * HEADS + hB];
  const float4* H4 = reinterpret_cast<const float4*>(H);
  float4 acc = {0.f, 0.f, 0.f, 0.f};
  int sv_nxt = 0;
  if (start < end) sv_nxt = src[eidx[start]];
  for (int i = start; i < end; ++i) {
    int sv = sv_nxt;
    if (i + 1 < end) sv_nxt = src[eidx[i + 1]];
    float sc = s0[sv * HEADS + hB] + s1B;
    sc = sc > 0.f ? sc : NEG_SLOPE * sc;
    float alpha = expf(sc) / denom;
    float4 hr = H4[(size_t)sv * 64 + lane];
    acc.x += alpha * hr.x; acc.y += alpha * hr.y;
    acc.z += alpha * hr.z; acc.w += alpha * hr.w;
  }
  float4* o = reinterpret_cast<float4*>(Hsum) + (size_t)v * 64 + lane;
  float4 prev = *o;
  prev.x += acc.x; prev.y += acc.y; prev.z += acc.z; prev.w += acc.w;
  *o = prev;
}

// ---------- X -> bf16 hi/lo split, K padded to K_PAD ----------
__global__ __launch_bounds__(256) void k_cvt_X(
    const float* __restrict__ X, unsigned short* __restrict__ Xhi,
    unsigned short* __restrict__ Xlo) {
  int row = blockIdx.y;
  int k0 = (blockIdx.x * 256 + threadIdx.x) * 8;
  if (k0 >= K_PAD) return;
  u16x8 hi, lo;
  if (k0 < K_DIM) {  // K_DIM divisible by 8 -> full vector
    const float4* p = reinterpret_cast<const float4*>(X + (size_t)row * K_DIM + k0);
    float4 x0 = p[0], x1 = p[1];
    float xs[8] = {x0.x, x0.y, x0.z, x0.w, x1.x, x1.y, x1.z, x1.w};
    #pragma unroll
    for (int j = 0; j < 8; ++j) {
      unsigned short h = f2bf_rtn(xs[j]);
      hi[j] = h;
      lo[j] = f2bf_rtn(xs[j] - bf2f(h));
    }
  } else {
    #pragma unroll
    for (int j = 0; j < 8; ++j) { hi[j] = 0; lo[j] = 0; }
  }
  *reinterpret_cast<u16x8*>(Xhi + (size_t)row * K_PAD + k0) = hi;
  *reinterpret_cast<u16x8*>(Xlo + (size_t)row * K_PAD + k0) = lo;
}

// ---------- Hsum -> transposed bf16 hi/lo split: Bt[h][k], K padded ----------
__global__ __launch_bounds__(256) void k_cvt_B(
    const float* __restrict__ Hs, unsigned short* __restrict__ Bthi,
    unsigned short* __restrict__ Btlo) {
  __shared__ float tile[64][65];
  const int t = threadIdx.x;
  const int v0 = blockIdx.x * 64;  // 470 blocks -> covers K_PAD
  const int h0 = blockIdx.y * 64;
  #pragma unroll
  for (int i = 0; i < 16; ++i) {
    int vloc = (t >> 6) + i * 4;
    int v = v0 + vloc;
    float f = (v < V_N) ? Hs[(size_t)v * HID + h0 + (t & 63)] : 0.f;
    tile[vloc][t & 63] = f;
  }
  __syncthreads();
  #pragma unroll
  for (int j = 0; j < 16; ++j) {
    int hloc = (t >> 6) + j * 4;
    int vloc = t & 63;
    float f = tile[vloc][hloc];
    unsigned short h = f2bf_rtn(f);
    unsigned short l = f2bf_rtn(f - bf2f(h));
    size_t o = (size_t)(h0 + hloc) * K_PAD + v0 + vloc;
    Bthi[o] = h;
    Btlo[o] = l;
  }
}

// ---------- Big GEMM: fused += X @ Hsum via bf16 MFMA, 3-product split ----------
__global__ __launch_bounds__(256) void k_gemm1_mfma(
    const unsigned short* __restrict__ Xhi, const unsigned short* __restrict__ Xlo,
    const unsigned short* __restrict__ Bthi, const unsigned short* __restrict__ Btlo,
    float* __restrict__ fused) {
  const int lane = threadIdx.x & 63;
  const int wave = threadIdx.x >> 6;
  const int m0 = blockIdx.x * 64;
  const int n0 = blockIdx.y * 64 + wave * 16;
  const int sbase = blockIdx.z * STEPS_Z;
  const int r = lane & 15;
  const int koff = (lane >> 4) * 8;
  f32x4 acc[4] = {{0,0,0,0},{0,0,0,0},{0,0,0,0},{0,0,0,0}};
  size_t aoff[4];
  #pragma unroll
  for (int i = 0; i < 4; ++i) aoff[i] = (size_t)(m0 + 16 * i + r) * K_PAD + koff;
  const size_t boff = (size_t)(n0 + r) * K_PAD + koff;
  for (int s = 0; s < STEPS_Z; ++s) {
    const int kk = (sbase + s) * 32;
    bf16x8 bhv = *reinterpret_cast<const bf16x8*>(Bthi + boff + kk);
    bf16x8 blv = *reinterpret_cast<const bf16x8*>(Btlo + boff + kk);
    #pragma unroll
    for (int i = 0; i < 4; ++i) {
      bf16x8 ahv = *reinterpret_cast<const bf16x8*>(Xhi + aoff[i] + kk);
      bf16x8 alv = *reinterpret_cast<const bf16x8*>(Xlo + aoff[i] + kk);
      acc[i] = __builtin_amdgcn_mfma_f32_16x16x32_bf16(ahv, bhv, acc[i], 0, 0, 0);
      acc[i] = __builtin_amdgcn_mfma_f32_16x16x32_bf16(ahv, blv, acc[i], 0, 0, 0);
      acc[i] = __builtin_amdgcn_mfma_f32_16x16x32_bf16(alv, bhv, acc[i], 0, 0, 0);
    }
  }
  const int colg = n0 + r;
  #pragma unroll
  for (int i = 0; i < 4; ++i) {
    int rowb = m0 + 16 * i + (lane >> 4) * 4;
    #pragma unroll
    for (int j = 0; j < 4; ++j)
      unsafeAtomicAdd(&fused[(size_t)(rowb + j) * HID + colg], acc[i][j]);
  }
}

// ---------- fallback fp32 GEMM (if ws too small for split buffers) ----------
__global__ __launch_bounds__(256) void k_gemm1_f32(
    const float* __restrict__ X, const float* __restrict__ Hs,
    float* __restrict__ fused) {
  __shared__ float As[32][132];
  __shared__ float Bs[32][64];
  const int t = threadIdx.x;
  const int m0 = blockIdx.x * 128, n0 = blockIdx.y * 64;
  const int k0 = blockIdx.z * 940;
  const int kend = min(k0 + 940, K_DIM);
  const int tm = t >> 4, tn = t & 15;
  float acc[8][4] = {};
  for (int kb = k0; kb < kend; kb += 32) {
    #pragma unroll
    for (int p = 0; p < 4; ++p) {
      int m = (t >> 3) + p * 32;
      int kl = (t & 7) * 4;
      float4 xv = {0.f, 0.f, 0.f, 0.f};
      if (kb + kl < kend)  // chunk bounds are multiples of 4
        xv = *reinterpret_cast<const float4*>(&X[(size_t)(m0 + m) * K_DIM + kb + kl]);
      As[kl + 0][m] = xv.x; As[kl + 1][m] = xv.y;
      As[kl + 2][m] = xv.z; As[kl + 3][m] = xv.w;
    }
    #pragma unroll
    for (int p = 0; p < 2; ++p) {
      int kl = (t >> 4) + p * 16;
      int nn = (t & 15) * 4;
      float4 bv = {0.f, 0.f, 0.f, 0.f};
      if (kb + kl < kend)
        bv = *reinterpret_cast<const float4*>(&Hs[(size_t)(kb + kl) * HID + n0 + nn]);
      *reinterpret_cast<float4*>(&Bs[kl][nn]) = bv;
    }
    __syncthreads();
    #pragma unroll 8
    for (int k = 0; k < 32; ++k) {
      float4 a0 = *reinterpret_cast<const float4*>(&As[k][tm * 8]);
      float4 a1 = *reinterpret_cast<const float4*>(&As[k][tm * 8 + 4]);
      float4 b  = *reinterpret_cast<const float4*>(&Bs[k][tn * 4]);
      float av[8] = {a0.x, a0.y, a0.z, a0.w, a1.x, a1.y, a1.z, a1.w};
      float bv[4] = {b.x, b.y, b.z, b.w};
      #pragma unroll
      for (int ii = 0; ii < 8; ++ii)
        #pragma unroll
        for (int j = 0; j < 4; ++j)
          acc[ii][j] += av[ii] * bv[j];
    }
    __syncthreads();
  }
  #pragma unroll
  for (int ii = 0; ii < 8; ++ii)
    #pragma unroll
    for (int j = 0; j < 4; ++j)
      unsafeAtomicAdd(&fused[(size_t)(m0 + tm * 8 + ii) * HID + n0 + tn * 4 + j],
                      acc[ii][j]);
}

// ---------- out = fused @ fc_w^T + fc_b ----------
__global__ __launch_bounds__(256) void k_gemm2(
    const float* __restrict__ fused, const float* __restrict__ fc_w,
    const float* __restrict__ fc_b, float* __restrict__ out) {
  int bd = blockIdx.x, o = threadIdx.x;
  __shared__ float fs[HID];
  fs[o] = fused[(size_t)bd * HID + o];
  __syncthreads();
  float acc = fc_b[o];
  const float* wr = fc_w + (size_t)o * HID;
  #pragma unroll 8
  for (int h = 0; h < HID; ++h) acc += fs[h] * wr[h];
  out[(size_t)bd * HID + o] = acc;
}

extern "C" void kernel_launch(void* const* d_in, const int* in_sizes, int n_in,
                              void* d_out, int out_size, void* d_ws, size_t ws_size,
                              hipStream_t stream) {
  const float* X    = (const float*)d_in[0];
  const float* W0   = (const float*)d_in[1];
  const float* a0   = (const float*)d_in[2];
  const float* W1   = (const float*)d_in[3];
  const float* a1   = (const float*)d_in[4];
  const float* fc_w = (const float*)d_in[5];
  const float* fc_b = (const float*)d_in[6];
  const float* val0 = (const float*)d_in[7];
  const float* val1 = (const float*)d_in[8];
  const int*   src0 = (const int*)d_in[9];
  const int*   dst0 = (const int*)d_in[10];
  const int*   src1 = (const int*)d_in[11];
  const int*   dst1 = (const int*)d_in[12];
  float* out = (float*)d_out;

  char* ws = (char*)d_ws;
  size_t off = 0;
  auto alloc = [&](size_t bytes) {
    void* p = ws + off;
    off += (bytes + 255) & ~(size_t)255;
    return p;
  };
  int*   deg     = (int*)alloc(4 * (size_t)V_N * 4);
  int*   rowptrs = (int*)alloc(4 * (size_t)(V_N + 1) * 4);
  int*   cursors = (int*)alloc(4 * (size_t)V_N * 4);
  int*   eidx    = (int*)alloc(4 * (size_t)E_N * 4);
  float* H       = (float*)alloc((size_t)V_N * HID * 4);
  float* Hsum    = (float*)alloc((size_t)V_N * HID * 4);
  float* s0      = (float*)alloc((size_t)V_N * HEADS * 4);
  float* s1      = (float*)alloc((size_t)V_N * HEADS * 4);
  float* fused   = (float*)alloc((size_t)M_ROWS * HID * 4);
  // MFMA-path extras
  unsigned short* Xhi  = (unsigned short*)alloc((size_t)M_ROWS * K_PAD * 2);
  unsigned short* Xlo  = (unsigned short*)alloc((size_t)M_ROWS * K_PAD * 2);
  unsigned short* Bthi = (unsigned short*)alloc((size_t)HID * K_PAD * 2);
  unsigned short* Btlo = (unsigned short*)alloc((size_t)HID * K_PAD * 2);
  const bool use_mfma = (off <= ws_size);

  hipMemsetAsync(deg, 0, 4 * (size_t)V_N * 4, stream);
  hipMemsetAsync(Hsum, 0, (size_t)V_N * HID * 4, stream);
  hipMemsetAsync(fused, 0, (size_t)M_ROWS * HID * 4, stream);

  const int EB = (E_N + 255) / 256;
  k_hist<<<EB, 256, 0, stream>>>(src0, dst0, src1, dst1, deg);
  k_scan4<<<4, 1024, 0, stream>>>(deg, rowptrs, cursors);
  k_fill<<<EB, 256, 0, stream>>>(src0, dst0, src1, dst1, cursors, eidx);

  const int VB = (V_N + 3) / 4;
  for (int g = 0; g < 2; ++g) {
    const float* W   = g ? W1 : W0;
    const float* a   = g ? a1 : a0;
    const float* val = g ? val1 : val0;
    const int* src   = g ? src1 : src0;
    const int* dst   = g ? dst1 : dst0;
    const int* rp_s  = rowptrs + (g * 2 + 0) * (V_N + 1);
    const int* rp_d  = rowptrs + (g * 2 + 1) * (V_N + 1);
    const int* ei_s  = eidx + (size_t)(g * 2 + 0) * E_N;
    const int* ei_d  = eidx + (size_t)(g * 2 + 1) * E_N;

    k_gather_H<<<VB, 256, 0, stream>>>(rp_s, ei_s, dst, val, W, a, H, s0, s1);
    k_fused_agg<<<VB, 256, 0, stream>>>(rp_d, ei_d, src, s0, s1, H, Hsum);
  }

  if (use_mfma) {
    k_cvt_X<<<dim3(15, M_ROWS), 256, 0, stream>>>(X, Xhi, Xlo);
    k_cvt_B<<<dim3(K_PAD / 64, HID / 64), 256, 0, stream>>>(Hsum, Bthi, Btlo);
    k_gemm1_mfma<<<dim3(M_ROWS / 64, HID / 64, SK_MFMA), 256, 0, stream>>>(
        Xhi, Xlo, Bthi, Btlo, fused);
  } else {
    k_gemm1_f32<<<dim3(M_ROWS / 128, HID / 64, 32), 256, 0, stream>>>(X, Hsum, fused);
  }
  k_gemm2<<<M_ROWS, 256, 0, stream>>>(fused, fc_w, fc_b, out);
}

// Round 4
// 901.117 us; speedup vs baseline: 7.9205x; 1.1100x over previous
//
#include <hip/hip_runtime.h>
#include <hip/hip_bf16.h>
#include <cstddef>

#define V_N 30000
#define E_N 480000
#define HID 256
#define HEADS 4
#define HD 64
#define M_ROWS 1024   // 2*512
#define K_DIM 30000
#define K_PAD 30080   // 20 * 47 * 32
#define SK_MFMA 20
#define STEPS_Z 47
#define NEG_SLOPE 0.2f
#define EPS_F 1e-9f

typedef __attribute__((ext_vector_type(8))) short bf16x8;
typedef __attribute__((ext_vector_type(4))) float f32x4;
typedef __attribute__((ext_vector_type(8))) unsigned short u16x8;
typedef __attribute__((ext_vector_type(4))) unsigned short u16x4;

__device__ inline unsigned short f2bf_rtn(float f) {
  unsigned u = __float_as_uint(f);
  unsigned r = u + 0x7fffu + ((u >> 16) & 1u);
  return (unsigned short)(r >> 16);
}
__device__ inline float bf2f(unsigned short h) {
  return __uint_as_float(((unsigned)h) << 16);
}

// ---------- CSR build: histogram ----------
__global__ __launch_bounds__(256) void k_hist(
    const int* __restrict__ s0g, const int* __restrict__ d0g,
    const int* __restrict__ s1g, const int* __restrict__ d1g,
    int* __restrict__ deg) {
  int e = blockIdx.x * 256 + threadIdx.x;
  if (e >= E_N) return;
  atomicAdd(&deg[0 * V_N + s0g[e]], 1);
  atomicAdd(&deg[1 * V_N + d0g[e]], 1);
  atomicAdd(&deg[2 * V_N + s1g[e]], 1);
  atomicAdd(&deg[3 * V_N + d1g[e]], 1);
}

// ---------- CSR build: 4 independent exclusive scans ----------
__global__ __launch_bounds__(1024) void k_scan4(
    const int* __restrict__ deg, int* __restrict__ rowptrs, int* __restrict__ cursors) {
  const int* dg = deg + blockIdx.x * V_N;
  int* rp = rowptrs + blockIdx.x * (V_N + 1);
  int* cur = cursors + blockIdx.x * V_N;
  __shared__ int part[1024];
  const int t = threadIdx.x;
  const int C = (V_N + 1023) / 1024;  // 30
  int base = t * C;
  int loc[C];
  int s = 0;
  #pragma unroll
  for (int i = 0; i < C; ++i) {
    int idx = base + i;
    int d = (idx < V_N) ? dg[idx] : 0;
    loc[i] = s;
    s += d;
  }
  part[t] = s;
  __syncthreads();
  for (int off = 1; off < 1024; off <<= 1) {
    int v_ = (t >= off) ? part[t - off] : 0;
    __syncthreads();
    part[t] += v_;
    __syncthreads();
  }
  int pre = (t == 0) ? 0 : part[t - 1];
  #pragma unroll
  for (int i = 0; i < C; ++i) {
    int idx = base + i;
    if (idx < V_N) {
      int v_ = pre + loc[i];
      rp[idx] = v_;
      cur[idx] = v_;
    }
  }
  if (t == 1023) rp[V_N] = part[1023];
}

// ---------- CSR build: fill edge indices ----------
__global__ __launch_bounds__(256) void k_fill(
    const int* __restrict__ s0g, const int* __restrict__ d0g,
    const int* __restrict__ s1g, const int* __restrict__ d1g,
    int* __restrict__ cursors, int* __restrict__ eidx) {
  int e = blockIdx.x * 256 + threadIdx.x;
  if (e >= E_N) return;
  int p;
  p = atomicAdd(&cursors[0 * V_N + s0g[e]], 1); eidx[0 * (size_t)E_N + p] = e;
  p = atomicAdd(&cursors[1 * V_N + d0g[e]], 1); eidx[1 * (size_t)E_N + p] = e;
  p = atomicAdd(&cursors[2 * V_N + s1g[e]], 1); eidx[2 * (size_t)E_N + p] = e;
  p = atomicAdd(&cursors[3 * V_N + d1g[e]], 1); eidx[3 * (size_t)E_N + p] = e;
}

// ---------- Phase 1+2: H gather (writes bf16 H) + fused score precompute ----------
__global__ __launch_bounds__(256) void k_gather_H(
    const int* __restrict__ rp, const int* __restrict__ eidx,
    const int* __restrict__ dst, const float* __restrict__ val,
    const float* __restrict__ W, const float* __restrict__ a,
    unsigned short* __restrict__ Hb, float* __restrict__ s0, float* __restrict__ s1) {
  int v = blockIdx.x * 4 + (threadIdx.x >> 6);
  if (v >= V_N) return;
  int lane = threadIdx.x & 63;
  int start = rp[v], end = rp[v + 1];
  const float4* W4 = reinterpret_cast<const float4*>(W);
  float4 acc = {0.f, 0.f, 0.f, 0.f};
  int d_nxt = 0; float f_nxt = 0.f;
  if (start < end) { int e = eidx[start]; d_nxt = dst[e]; f_nxt = val[e]; }
  for (int i = start; i < end; ++i) {
    int d = d_nxt; float f = f_nxt;
    if (i + 1 < end) { int e = eidx[i + 1]; d_nxt = dst[e]; f_nxt = val[e]; }
    float4 w = W4[(size_t)d * 64 + lane];
    acc.x += f * w.x; acc.y += f * w.y; acc.z += f * w.z; acc.w += f * w.w;
  }
  u16x4 hb;
  hb[0] = f2bf_rtn(acc.x); hb[1] = f2bf_rtn(acc.y);
  hb[2] = f2bf_rtn(acc.z); hb[3] = f2bf_rtn(acc.w);
  *(reinterpret_cast<u16x4*>(Hb) + (size_t)v * 64 + lane) = hb;
  int h = lane >> 4, dd = (lane & 15) * 4;
  const float* ah = a + h * (2 * HD);
  float p0 = acc.x * ah[dd] + acc.y * ah[dd + 1] + acc.z * ah[dd + 2] + acc.w * ah[dd + 3];
  float p1 = acc.x * ah[HD + dd] + acc.y * ah[HD + dd + 1] + acc.z * ah[HD + dd + 2] + acc.w * ah[HD + dd + 3];
  #pragma unroll
  for (int off = 1; off < 16; off <<= 1) {
    p0 += __shfl_xor(p0, off);
    p1 += __shfl_xor(p1, off);
  }
  if ((lane & 15) == 0) {
    s0[v * HEADS + h] = p0;
    s1[v * HEADS + h] = p1;
  }
}

// ---------- Phase 3+4: softmax denom + aggregation (bf16 H gather) ----------
__global__ __launch_bounds__(256) void k_fused_agg(
    const int* __restrict__ rp, const int* __restrict__ eidx,
    const int* __restrict__ src, const float* __restrict__ s0,
    const float* __restrict__ s1, const unsigned short* __restrict__ Hb,
    float* __restrict__ Hsum) {
  int v = blockIdx.x * 4 + (threadIdx.x >> 6);
  if (v >= V_N) return;
  int lane = threadIdx.x & 63;
  int start = rp[v], end = rp[v + 1];
  int hA = lane & 3, idx = lane >> 2;
  float s1A = s1[v * HEADS + hA];
  float dsum = 0.f;
  for (int i0 = start; i0 < end; i0 += 16) {
    int i = i0 + idx;
    if (i < end) {
      int e = eidx[i];
      int sv = src[e];
      float sc = s0[sv * HEADS + hA] + s1A;
      sc = sc > 0.f ? sc : NEG_SLOPE * sc;
      dsum += expf(sc);
    }
  }
  #pragma unroll
  for (int off = 4; off < 64; off <<= 1) dsum += __shfl_xor(dsum, off);
  int hB = lane >> 4;
  float denom = __shfl(dsum, hB) + EPS_F;
  float s1B = s1[v * HEADS + hB];
  const u16x4* H4 = reinterpret_cast<const u16x4*>(Hb);
  float4 acc = {0.f, 0.f, 0.f, 0.f};
  int sv_nxt = 0;
  if (start < end) sv_nxt = src[eidx[start]];
  for (int i = start; i < end; ++i) {
    int sv = sv_nxt;
    if (i + 1 < end) sv_nxt = src[eidx[i + 1]];
    float sc = s0[sv * HEADS + hB] + s1B;
    sc = sc > 0.f ? sc : NEG_SLOPE * sc;
    float alpha = expf(sc) / denom;
    u16x4 hr = H4[(size_t)sv * 64 + lane];
    acc.x += alpha * bf2f(hr[0]); acc.y += alpha * bf2f(hr[1]);
    acc.z += alpha * bf2f(hr[2]); acc.w += alpha * bf2f(hr[3]);
  }
  float4* o = reinterpret_cast<float4*>(Hsum) + (size_t)v * 64 + lane;
  float4 prev = *o;
  prev.x += acc.x; prev.y += acc.y; prev.z += acc.z; prev.w += acc.w;
  *o = prev;
}

// ---------- X -> bf16 (hi only), K padded to K_PAD ----------
__global__ __launch_bounds__(256) void k_cvt_X(
    const float* __restrict__ X, unsigned short* __restrict__ Xhi) {
  int row = blockIdx.y;
  int k0 = (blockIdx.x * 256 + threadIdx.x) * 8;
  if (k0 >= K_PAD) return;
  u16x8 hi;
  if (k0 < K_DIM) {
    const float4* p = reinterpret_cast<const float4*>(X + (size_t)row * K_DIM + k0);
    float4 x0 = p[0], x1 = p[1];
    float xs[8] = {x0.x, x0.y, x0.z, x0.w, x1.x, x1.y, x1.z, x1.w};
    #pragma unroll
    for (int j = 0; j < 8; ++j) hi[j] = f2bf_rtn(xs[j]);
  } else {
    #pragma unroll
    for (int j = 0; j < 8; ++j) hi[j] = 0;
  }
  *reinterpret_cast<u16x8*>(Xhi + (size_t)row * K_PAD + k0) = hi;
}

// ---------- Hsum -> transposed bf16 hi/lo split: Bt[h][k], K padded ----------
__global__ __launch_bounds__(256) void k_cvt_B(
    const float* __restrict__ Hs, unsigned short* __restrict__ Bthi,
    unsigned short* __restrict__ Btlo) {
  __shared__ float tile[64][65];
  const int t = threadIdx.x;
  const int v0 = blockIdx.x * 64;
  const int h0 = blockIdx.y * 64;
  #pragma unroll
  for (int i = 0; i < 16; ++i) {
    int vloc = (t >> 6) + i * 4;
    int v = v0 + vloc;
    float f = (v < V_N) ? Hs[(size_t)v * HID + h0 + (t & 63)] : 0.f;
    tile[vloc][t & 63] = f;
  }
  __syncthreads();
  #pragma unroll
  for (int j = 0; j < 16; ++j) {
    int hloc = (t >> 6) + j * 4;
    int vloc = t & 63;
    float f = tile[vloc][hloc];
    unsigned short h = f2bf_rtn(f);
    unsigned short l = f2bf_rtn(f - bf2f(h));
    size_t o = (size_t)(h0 + hloc) * K_PAD + v0 + vloc;
    Bthi[o] = h;
    Btlo[o] = l;
  }
}

// ---------- Big GEMM: fused += X @ Hsum; X read once (ny=1), 2-product ----------
__global__ __launch_bounds__(512) void k_gemm1_mfma(
    const unsigned short* __restrict__ Xhi,
    const unsigned short* __restrict__ Bthi, const unsigned short* __restrict__ Btlo,
    float* __restrict__ fused) {
  const int lane = threadIdx.x & 63;
  const int wave = threadIdx.x >> 6;   // 0..7
  const int mw = wave >> 2;            // 0..1
  const int nw = wave & 3;             // 0..3
  const int m0 = blockIdx.x * 64 + mw * 32;
  const int n0 = nw * 64;
  const int r = lane & 15;
  const int koff = (lane >> 4) * 8;
  const size_t kbase = (size_t)blockIdx.z * (STEPS_Z * 32) + koff;

  f32x4 acc[2][4] = {};
  const unsigned short* A0 = Xhi + (size_t)(m0 + r) * K_PAD + kbase;
  const unsigned short* A1 = Xhi + (size_t)(m0 + 16 + r) * K_PAD + kbase;
  const unsigned short* Bh[4];
  const unsigned short* Bl[4];
  #pragma unroll
  for (int j = 0; j < 4; ++j) {
    size_t o = (size_t)(n0 + 16 * j + r) * K_PAD + kbase;
    Bh[j] = Bthi + o;
    Bl[j] = Btlo + o;
  }
  for (int s = 0; s < STEPS_Z; ++s) {
    const int kk = s * 32;
    bf16x8 a0 = *reinterpret_cast<const bf16x8*>(A0 + kk);
    bf16x8 a1 = *reinterpret_cast<const bf16x8*>(A1 + kk);
    bf16x8 bh[4], bl[4];
    #pragma unroll
    for (int j = 0; j < 4; ++j) {
      bh[j] = *reinterpret_cast<const bf16x8*>(Bh[j] + kk);
      bl[j] = *reinterpret_cast<const bf16x8*>(Bl[j] + kk);
    }
    #pragma unroll
    for (int j = 0; j < 4; ++j) {
      acc[0][j] = __builtin_amdgcn_mfma_f32_16x16x32_bf16(a0, bh[j], acc[0][j], 0, 0, 0);
      acc[1][j] = __builtin_amdgcn_mfma_f32_16x16x32_bf16(a1, bh[j], acc[1][j], 0, 0, 0);
    }
    #pragma unroll
    for (int j = 0; j < 4; ++j) {
      acc[0][j] = __builtin_amdgcn_mfma_f32_16x16x32_bf16(a0, bl[j], acc[0][j], 0, 0, 0);
      acc[1][j] = __builtin_amdgcn_mfma_f32_16x16x32_bf16(a1, bl[j], acc[1][j], 0, 0, 0);
    }
  }
  const int rowoff = (lane >> 4) * 4;
  #pragma unroll
  for (int i = 0; i < 2; ++i) {
    int rowb = m0 + 16 * i + rowoff;
    #pragma unroll
    for (int j = 0; j < 4; ++j) {
      int colg = n0 + 16 * j + r;
      #pragma unroll
      for (int jj = 0; jj < 4; ++jj)
        unsafeAtomicAdd(&fused[(size_t)(rowb + jj) * HID + colg], acc[i][j][jj]);
    }
  }
}

// ---------- out = fused @ fc_w^T + fc_b ----------
__global__ __launch_bounds__(256) void k_gemm2(
    const float* __restrict__ fused, const float* __restrict__ fc_w,
    const float* __restrict__ fc_b, float* __restrict__ out) {
  int bd = blockIdx.x, o = threadIdx.x;
  __shared__ float fs[HID];
  fs[o] = fused[(size_t)bd * HID + o];
  __syncthreads();
  float acc = fc_b[o];
  const float* wr = fc_w + (size_t)o * HID;
  #pragma unroll 8
  for (int h = 0; h < HID; ++h) acc += fs[h] * wr[h];
  out[(size_t)bd * HID + o] = acc;
}

extern "C" void kernel_launch(void* const* d_in, const int* in_sizes, int n_in,
                              void* d_out, int out_size, void* d_ws, size_t ws_size,
                              hipStream_t stream) {
  const float* X    = (const float*)d_in[0];
  const float* W0   = (const float*)d_in[1];
  const float* a0   = (const float*)d_in[2];
  const float* W1   = (const float*)d_in[3];
  const float* a1   = (const float*)d_in[4];
  const float* fc_w = (const float*)d_in[5];
  const float* fc_b = (const float*)d_in[6];
  const float* val0 = (const float*)d_in[7];
  const float* val1 = (const float*)d_in[8];
  const int*   src0 = (const int*)d_in[9];
  const int*   dst0 = (const int*)d_in[10];
  const int*   src1 = (const int*)d_in[11];
  const int*   dst1 = (const int*)d_in[12];
  float* out = (float*)d_out;

  char* ws = (char*)d_ws;
  size_t off = 0;
  auto alloc = [&](size_t bytes) {
    void* p = ws + off;
    off += (bytes + 255) & ~(size_t)255;
    return p;
  };
  int*   deg     = (int*)alloc(4 * (size_t)V_N * 4);
  int*   rowptrs = (int*)alloc(4 * (size_t)(V_N + 1) * 4);
  int*   cursors = (int*)alloc(4 * (size_t)V_N * 4);
  int*   eidx    = (int*)alloc(4 * (size_t)E_N * 4);
  unsigned short* Hb = (unsigned short*)alloc((size_t)V_N * HID * 2);
  float* Hsum    = (float*)alloc((size_t)V_N * HID * 4);
  float* s0      = (float*)alloc((size_t)V_N * HEADS * 4);
  float* s1      = (float*)alloc((size_t)V_N * HEADS * 4);
  float* fused   = (float*)alloc((size_t)M_ROWS * HID * 4);
  unsigned short* Xhi  = (unsigned short*)alloc((size_t)M_ROWS * K_PAD * 2);
  unsigned short* Bthi = (unsigned short*)alloc((size_t)HID * K_PAD * 2);
  unsigned short* Btlo = (unsigned short*)alloc((size_t)HID * K_PAD * 2);

  hipMemsetAsync(deg, 0, 4 * (size_t)V_N * 4, stream);
  hipMemsetAsync(Hsum, 0, (size_t)V_N * HID * 4, stream);
  hipMemsetAsync(fused, 0, (size_t)M_ROWS * HID * 4, stream);

  const int EB = (E_N + 255) / 256;
  k_hist<<<EB, 256, 0, stream>>>(src0, dst0, src1, dst1, deg);
  k_scan4<<<4, 1024, 0, stream>>>(deg, rowptrs, cursors);
  k_fill<<<EB, 256, 0, stream>>>(src0, dst0, src1, dst1, cursors, eidx);

  // X conversion is independent of the graph phases
  k_cvt_X<<<dim3(15, M_ROWS), 256, 0, stream>>>(X, Xhi);

  const int VB = (V_N + 3) / 4;
  for (int g = 0; g < 2; ++g) {
    const float* W   = g ? W1 : W0;
    const float* a   = g ? a1 : a0;
    const float* val = g ? val1 : val0;
    const int* src   = g ? src1 : src0;
    const int* dst   = g ? dst1 : dst0;
    const int* rp_s  = rowptrs + (g * 2 + 0) * (V_N + 1);
    const int* rp_d  = rowptrs + (g * 2 + 1) * (V_N + 1);
    const int* ei_s  = eidx + (size_t)(g * 2 + 0) * E_N;
    const int* ei_d  = eidx + (size_t)(g * 2 + 1) * E_N;

    k_gather_H<<<VB, 256, 0, stream>>>(rp_s, ei_s, dst, val, W, a, Hb, s0, s1);
    k_fused_agg<<<VB, 256, 0, stream>>>(rp_d, ei_d, src, s0, s1, Hb, Hsum);
  }

  k_cvt_B<<<dim3(K_PAD / 64, HID / 64), 256, 0, stream>>>(Hsum, Bthi, Btlo);
  k_gemm1_mfma<<<dim3(M_ROWS / 64, 1, SK_MFMA), 512, 0, stream>>>(Xhi, Bthi, Btlo, fused);
  k_gemm2<<<M_ROWS, 256, 0, stream>>>(fused, fc_w, fc_b, out);
}

// Round 6
// 831.952 us; speedup vs baseline: 8.5789x; 1.0831x over previous
//
#include <hip/hip_runtime.h>
#include <hip/hip_bf16.h>
#include <cstddef>

#define V_N 30000
#define E_N 480000
#define HID 256
#define HEADS 4
#define HD 64
#define M_ROWS 1024   // 2*512
#define K_DIM 30000
#define K_PAD 30080   // 47 * 20 * 32
#define SK_MFMA 47
#define STEPS_Z 20
#define NEG_SLOPE 0.2f
#define EPS_F 1e-9f

typedef __attribute__((ext_vector_type(8))) short bf16x8;
typedef __attribute__((ext_vector_type(4))) float f32x4;
typedef __attribute__((ext_vector_type(8))) unsigned short u16x8;
typedef __attribute__((ext_vector_type(4))) unsigned short u16x4;

__device__ inline unsigned short f2bf_rtn(float f) {
  unsigned u = __float_as_uint(f);
  unsigned r = u + 0x7fffu + ((u >> 16) & 1u);
  return (unsigned short)(r >> 16);
}
__device__ inline float bf2f(unsigned short h) {
  return __uint_as_float(((unsigned)h) << 16);
}

// ---------- CSR build: histogram ----------
__global__ __launch_bounds__(256) void k_hist(
    const int* __restrict__ s0g, const int* __restrict__ d0g,
    const int* __restrict__ s1g, const int* __restrict__ d1g,
    int* __restrict__ deg) {
  int e = blockIdx.x * 256 + threadIdx.x;
  if (e >= E_N) return;
  atomicAdd(&deg[0 * V_N + s0g[e]], 1);
  atomicAdd(&deg[1 * V_N + d0g[e]], 1);
  atomicAdd(&deg[2 * V_N + s1g[e]], 1);
  atomicAdd(&deg[3 * V_N + d1g[e]], 1);
}

// ---------- CSR build: 4 independent exclusive scans ----------
__global__ __launch_bounds__(1024) void k_scan4(
    const int* __restrict__ deg, int* __restrict__ rowptrs, int* __restrict__ cursors) {
  const int* dg = deg + blockIdx.x * V_N;
  int* rp = rowptrs + blockIdx.x * (V_N + 1);
  int* cur = cursors + blockIdx.x * V_N;
  __shared__ int part[1024];
  const int t = threadIdx.x;
  const int C = (V_N + 1023) / 1024;  // 30
  int base = t * C;
  int loc[C];
  int s = 0;
  #pragma unroll
  for (int i = 0; i < C; ++i) {
    int idx = base + i;
    int d = (idx < V_N) ? dg[idx] : 0;
    loc[i] = s;
    s += d;
  }
  part[t] = s;
  __syncthreads();
  for (int off = 1; off < 1024; off <<= 1) {
    int v_ = (t >= off) ? part[t - off] : 0;
    __syncthreads();
    part[t] += v_;
    __syncthreads();
  }
  int pre = (t == 0) ? 0 : part[t - 1];
  #pragma unroll
  for (int i = 0; i < C; ++i) {
    int idx = base + i;
    if (idx < V_N) {
      int v_ = pre + loc[i];
      rp[idx] = v_;
      cur[idx] = v_;
    }
  }
  if (t == 1023) rp[V_N] = part[1023];
}

// ---------- CSR build: fill edge indices ----------
__global__ __launch_bounds__(256) void k_fill(
    const int* __restrict__ s0g, const int* __restrict__ d0g,
    const int* __restrict__ s1g, const int* __restrict__ d1g,
    int* __restrict__ cursors, int* __restrict__ eidx) {
  int e = blockIdx.x * 256 + threadIdx.x;
  if (e >= E_N) return;
  int p;
  p = atomicAdd(&cursors[0 * V_N + s0g[e]], 1); eidx[0 * (size_t)E_N + p] = e;
  p = atomicAdd(&cursors[1 * V_N + d0g[e]], 1); eidx[1 * (size_t)E_N + p] = e;
  p = atomicAdd(&cursors[2 * V_N + s1g[e]], 1); eidx[2 * (size_t)E_N + p] = e;
  p = atomicAdd(&cursors[3 * V_N + d1g[e]], 1); eidx[3 * (size_t)E_N + p] = e;
}

// ---------- W -> bf16 ----------
__global__ __launch_bounds__(256) void k_cvt_W(
    const float* __restrict__ Wsrc, unsigned short* __restrict__ Wdst) {
  size_t i = ((size_t)blockIdx.x * 256 + threadIdx.x) * 8;
  const float4* p = reinterpret_cast<const float4*>(Wsrc + i);
  float4 x0 = p[0], x1 = p[1];
  float xs[8] = {x0.x, x0.y, x0.z, x0.w, x1.x, x1.y, x1.z, x1.w};
  u16x8 o;
  #pragma unroll
  for (int j = 0; j < 8; ++j) o[j] = f2bf_rtn(xs[j]);
  *reinterpret_cast<u16x8*>(Wdst + i) = o;
}

// ---------- Phase 1+2: H gather (bf16 W in, bf16 H out) + score precompute ----------
__global__ __launch_bounds__(256) void k_gather_H(
    const int* __restrict__ rp, const int* __restrict__ eidx,
    const int* __restrict__ dst, const float* __restrict__ val,
    const unsigned short* __restrict__ Wb, const float* __restrict__ a,
    unsigned short* __restrict__ Hb, float* __restrict__ s0, float* __restrict__ s1) {
  int v = blockIdx.x * 4 + (threadIdx.x >> 6);
  if (v >= V_N) return;
  int lane = threadIdx.x & 63;
  int start = rp[v], end = rp[v + 1];
  const u16x4* W4 = reinterpret_cast<const u16x4*>(Wb);
  float4 acc = {0.f, 0.f, 0.f, 0.f};
  int d_nxt = 0; float f_nxt = 0.f;
  if (start < end) { int e = eidx[start]; d_nxt = dst[e]; f_nxt = val[e]; }
  for (int i = start; i < end; ++i) {
    int d = d_nxt; float f = f_nxt;
    if (i + 1 < end) { int e = eidx[i + 1]; d_nxt = dst[e]; f_nxt = val[e]; }
    u16x4 w = W4[(size_t)d * 64 + lane];
    acc.x += f * bf2f(w[0]); acc.y += f * bf2f(w[1]);
    acc.z += f * bf2f(w[2]); acc.w += f * bf2f(w[3]);
  }
  u16x4 hb;
  hb[0] = f2bf_rtn(acc.x); hb[1] = f2bf_rtn(acc.y);
  hb[2] = f2bf_rtn(acc.z); hb[3] = f2bf_rtn(acc.w);
  *(reinterpret_cast<u16x4*>(Hb) + (size_t)v * 64 + lane) = hb;
  int h = lane >> 4, dd = (lane & 15) * 4;
  const float* ah = a + h * (2 * HD);
  float p0 = acc.x * ah[dd] + acc.y * ah[dd + 1] + acc.z * ah[dd + 2] + acc.w * ah[dd + 3];
  float p1 = acc.x * ah[HD + dd] + acc.y * ah[HD + dd + 1] + acc.z * ah[HD + dd + 2] + acc.w * ah[HD + dd + 3];
  #pragma unroll
  for (int off = 1; off < 16; off <<= 1) {
    p0 += __shfl_xor(p0, off);
    p1 += __shfl_xor(p1, off);
  }
  if ((lane & 15) == 0) {
    s0[v * HEADS + h] = p0;
    s1[v * HEADS + h] = p1;
  }
}

// ---------- Phase 3+4: softmax denom + aggregation (bf16 H gather) ----------
__global__ __launch_bounds__(256) void k_fused_agg(
    const int* __restrict__ rp, const int* __restrict__ eidx,
    const int* __restrict__ src, const float* __restrict__ s0,
    const float* __restrict__ s1, const unsigned short* __restrict__ Hb,
    float* __restrict__ Hsum) {
  int v = blockIdx.x * 4 + (threadIdx.x >> 6);
  if (v >= V_N) return;
  int lane = threadIdx.x & 63;
  int start = rp[v], end = rp[v + 1];
  int hA = lane & 3, idx = lane >> 2;
  float s1A = s1[v * HEADS + hA];
  float dsum = 0.f;
  for (int i0 = start; i0 < end; i0 += 16) {
    int i = i0 + idx;
    if (i < end) {
      int e = eidx[i];
      int sv = src[e];
      float sc = s0[sv * HEADS + hA] + s1A;
      sc = sc > 0.f ? sc : NEG_SLOPE * sc;
      dsum += expf(sc);
    }
  }
  #pragma unroll
  for (int off = 4; off < 64; off <<= 1) dsum += __shfl_xor(dsum, off);
  int hB = lane >> 4;
  float denom = __shfl(dsum, hB) + EPS_F;
  float s1B = s1[v * HEADS + hB];
  const u16x4* H4 = reinterpret_cast<const u16x4*>(Hb);
  float4 acc = {0.f, 0.f, 0.f, 0.f};
  int sv_nxt = 0;
  if (start < end) sv_nxt = src[eidx[start]];
  for (int i = start; i < end; ++i) {
    int sv = sv_nxt;
    if (i + 1 < end) sv_nxt = src[eidx[i + 1]];
    float sc = s0[sv * HEADS + hB] + s1B;
    sc = sc > 0.f ? sc : NEG_SLOPE * sc;
    float alpha = expf(sc) / denom;
    u16x4 hr = H4[(size_t)sv * 64 + lane];
    acc.x += alpha * bf2f(hr[0]); acc.y += alpha * bf2f(hr[1]);
    acc.z += alpha * bf2f(hr[2]); acc.w += alpha * bf2f(hr[3]);
  }
  float4* o = reinterpret_cast<float4*>(Hsum) + (size_t)v * 64 + lane;
  float4 prev = *o;
  prev.x += acc.x; prev.y += acc.y; prev.z += acc.z; prev.w += acc.w;
  *o = prev;
}

// ---------- X -> bf16 (hi only), K padded to K_PAD ----------
__global__ __launch_bounds__(256) void k_cvt_X(
    const float* __restrict__ X, unsigned short* __restrict__ Xhi) {
  int row = blockIdx.y;
  int k0 = (blockIdx.x * 256 + threadIdx.x) * 8;
  if (k0 >= K_PAD) return;
  u16x8 hi;
  if (k0 < K_DIM) {
    const float4* p = reinterpret_cast<const float4*>(X + (size_t)row * K_DIM + k0);
    float4 x0 = p[0], x1 = p[1];
    float xs[8] = {x0.x, x0.y, x0.z, x0.w, x1.x, x1.y, x1.z, x1.w};
    #pragma unroll
    for (int j = 0; j < 8; ++j) hi[j] = f2bf_rtn(xs[j]);
  } else {
    #pragma unroll
    for (int j = 0; j < 8; ++j) hi[j] = 0;
  }
  *reinterpret_cast<u16x8*>(Xhi + (size_t)row * K_PAD + k0) = hi;
}

// ---------- Hsum -> transposed bf16 hi/lo split: Bt[h][k], K padded ----------
__global__ __launch_bounds__(256) void k_cvt_B(
    const float* __restrict__ Hs, unsigned short* __restrict__ Bthi,
    unsigned short* __restrict__ Btlo) {
  __shared__ float tile[64][65];
  const int t = threadIdx.x;
  const int v0 = blockIdx.x * 64;
  const int h0 = blockIdx.y * 64;
  #pragma unroll
  for (int i = 0; i < 16; ++i) {
    int vloc = (t >> 6) + i * 4;
    int v = v0 + vloc;
    float f = (v < V_N) ? Hs[(size_t)v * HID + h0 + (t & 63)] : 0.f;
    tile[vloc][t & 63] = f;
  }
  __syncthreads();
  #pragma unroll
  for (int j = 0; j < 16; ++j) {
    int hloc = (t >> 6) + j * 4;
    int vloc = t & 63;
    float f = tile[vloc][hloc];
    unsigned short h = f2bf_rtn(f);
    unsigned short l = f2bf_rtn(f - bf2f(h));
    size_t o = (size_t)(h0 + hloc) * K_PAD + v0 + vloc;
    Bthi[o] = h;
    Btlo[o] = l;
  }
}

// ---------- Big GEMM: fused += X @ Hsum; SK=47, 2-deep register pipeline ----------
__global__ __launch_bounds__(512) void k_gemm1_mfma(
    const unsigned short* __restrict__ Xhi,
    const unsigned short* __restrict__ Bthi, const unsigned short* __restrict__ Btlo,
    float* __restrict__ fused) {
  const int lane = threadIdx.x & 63;
  const int wave = threadIdx.x >> 6;   // 0..7
  const int mw = wave >> 2;            // 0..1
  const int nw = wave & 3;             // 0..3
  const int m0 = blockIdx.x * 64 + mw * 32;
  const int n0 = nw * 64;
  const int r = lane & 15;
  const int koff = (lane >> 4) * 8;
  const size_t kbase = (size_t)blockIdx.z * (STEPS_Z * 32) + koff;

  f32x4 acc[2][4] = {};
  const unsigned short* A0 = Xhi + (size_t)(m0 + r) * K_PAD + kbase;
  const unsigned short* A1 = Xhi + (size_t)(m0 + 16 + r) * K_PAD + kbase;
  const unsigned short* Bh[4];
  const unsigned short* Bl[4];
  #pragma unroll
  for (int j = 0; j < 4; ++j) {
    size_t o = (size_t)(n0 + 16 * j + r) * K_PAD + kbase;
    Bh[j] = Bthi + o;
    Bl[j] = Btlo + o;
  }
  // prologue: load step 0
  bf16x8 a0 = *reinterpret_cast<const bf16x8*>(A0);
  bf16x8 a1 = *reinterpret_cast<const bf16x8*>(A1);
  bf16x8 bh[4], bl[4];
  #pragma unroll
  for (int j = 0; j < 4; ++j) {
    bh[j] = *reinterpret_cast<const bf16x8*>(Bh[j]);
    bl[j] = *reinterpret_cast<const bf16x8*>(Bl[j]);
  }
  for (int s = 0; s < STEPS_Z - 1; ++s) {
    const int nk = (s + 1) * 32;
    bf16x8 na0 = *reinterpret_cast<const bf16x8*>(A0 + nk);
    bf16x8 na1 = *reinterpret_cast<const bf16x8*>(A1 + nk);
    bf16x8 nbh[4], nbl[4];
    #pragma unroll
    for (int j = 0; j < 4; ++j) {
      nbh[j] = *reinterpret_cast<const bf16x8*>(Bh[j] + nk);
      nbl[j] = *reinterpret_cast<const bf16x8*>(Bl[j] + nk);
    }
    #pragma unroll
    for (int j = 0; j < 4; ++j) {
      acc[0][j] = __builtin_amdgcn_mfma_f32_16x16x32_bf16(a0, bh[j], acc[0][j], 0, 0, 0);
      acc[1][j] = __builtin_amdgcn_mfma_f32_16x16x32_bf16(a1, bh[j], acc[1][j], 0, 0, 0);
      acc[0][j] = __builtin_amdgcn_mfma_f32_16x16x32_bf16(a0, bl[j], acc[0][j], 0, 0, 0);
      acc[1][j] = __builtin_amdgcn_mfma_f32_16x16x32_bf16(a1, bl[j], acc[1][j], 0, 0, 0);
    }
    a0 = na0; a1 = na1;
    #pragma unroll
    for (int j = 0; j < 4; ++j) { bh[j] = nbh[j]; bl[j] = nbl[j]; }
  }
  #pragma unroll
  for (int j = 0; j < 4; ++j) {
    acc[0][j] = __builtin_amdgcn_mfma_f32_16x16x32_bf16(a0, bh[j], acc[0][j], 0, 0, 0);
    acc[1][j] = __builtin_amdgcn_mfma_f32_16x16x32_bf16(a1, bh[j], acc[1][j], 0, 0, 0);
    acc[0][j] = __builtin_amdgcn_mfma_f32_16x16x32_bf16(a0, bl[j], acc[0][j], 0, 0, 0);
    acc[1][j] = __builtin_amdgcn_mfma_f32_16x16x32_bf16(a1, bl[j], acc[1][j], 0, 0, 0);
  }
  const int rowoff = (lane >> 4) * 4;
  #pragma unroll
  for (int i = 0; i < 2; ++i) {
    int rowb = m0 + 16 * i + rowoff;
    #pragma unroll
    for (int j = 0; j < 4; ++j) {
      int colg = n0 + 16 * j + r;
      #pragma unroll
      for (int jj = 0; jj < 4; ++jj)
        unsafeAtomicAdd(&fused[(size_t)(rowb + jj) * HID + colg], acc[i][j][jj]);
    }
  }
}

// ---------- out = fused @ fc_w^T + fc_b ----------
__global__ __launch_bounds__(256) void k_gemm2(
    const float* __restrict__ fused, const float* __restrict__ fc_w,
    const float* __restrict__ fc_b, float* __restrict__ out) {
  int bd = blockIdx.x, o = threadIdx.x;
  __shared__ float fs[HID];
  fs[o] = fused[(size_t)bd * HID + o];
  __syncthreads();
  float acc = fc_b[o];
  const float* wr = fc_w + (size_t)o * HID;
  #pragma unroll 8
  for (int h = 0; h < HID; ++h) acc += fs[h] * wr[h];
  out[(size_t)bd * HID + o] = acc;
}

extern "C" void kernel_launch(void* const* d_in, const int* in_sizes, int n_in,
                              void* d_out, int out_size, void* d_ws, size_t ws_size,
                              hipStream_t stream) {
  const float* X    = (const float*)d_in[0];
  const float* W0   = (const float*)d_in[1];
  const float* a0   = (const float*)d_in[2];
  const float* W1   = (const float*)d_in[3];
  const float* a1   = (const float*)d_in[4];
  const float* fc_w = (const float*)d_in[5];
  const float* fc_b = (const float*)d_in[6];
  const float* val0 = (const float*)d_in[7];
  const float* val1 = (const float*)d_in[8];
  const int*   src0 = (const int*)d_in[9];
  const int*   dst0 = (const int*)d_in[10];
  const int*   src1 = (const int*)d_in[11];
  const int*   dst1 = (const int*)d_in[12];
  float* out = (float*)d_out;

  char* ws = (char*)d_ws;
  size_t off = 0;
  auto alloc = [&](size_t bytes) {
    void* p = ws + off;
    off += (bytes + 255) & ~(size_t)255;
    return p;
  };
  int*   deg     = (int*)alloc(4 * (size_t)V_N * 4);
  int*   rowptrs = (int*)alloc(4 * (size_t)(V_N + 1) * 4);
  int*   cursors = (int*)alloc(4 * (size_t)V_N * 4);
  int*   eidx    = (int*)alloc(4 * (size_t)E_N * 4);
  unsigned short* Hb  = (unsigned short*)alloc((size_t)V_N * HID * 2);
  unsigned short* Wb0 = (unsigned short*)alloc((size_t)V_N * HID * 2);
  unsigned short* Wb1 = (unsigned short*)alloc((size_t)V_N * HID * 2);
  float* Hsum    = (float*)alloc((size_t)V_N * HID * 4);
  float* s0      = (float*)alloc((size_t)V_N * HEADS * 4);
  float* s1      = (float*)alloc((size_t)V_N * HEADS * 4);
  float* fused   = (float*)alloc((size_t)M_ROWS * HID * 4);
  unsigned short* Xhi  = (unsigned short*)alloc((size_t)M_ROWS * K_PAD * 2);
  unsigned short* Bthi = (unsigned short*)alloc((size_t)HID * K_PAD * 2);
  unsigned short* Btlo = (unsigned short*)alloc((size_t)HID * K_PAD * 2);

  hipMemsetAsync(deg, 0, 4 * (size_t)V_N * 4, stream);
  hipMemsetAsync(Hsum, 0, (size_t)V_N * HID * 4, stream);
  hipMemsetAsync(fused, 0, (size_t)M_ROWS * HID * 4, stream);

  const int EB = (E_N + 255) / 256;
  k_hist<<<EB, 256, 0, stream>>>(src0, dst0, src1, dst1, deg);
  k_scan4<<<4, 1024, 0, stream>>>(deg, rowptrs, cursors);
  k_fill<<<EB, 256, 0, stream>>>(src0, dst0, src1, dst1, cursors, eidx);

  const int WB = (int)(((size_t)V_N * HID / 8 + 255) / 256);  // 3750
  k_cvt_W<<<WB, 256, 0, stream>>>(W0, Wb0);
  k_cvt_W<<<WB, 256, 0, stream>>>(W1, Wb1);
  k_cvt_X<<<dim3(15, M_ROWS), 256, 0, stream>>>(X, Xhi);

  const int VB = (V_N + 3) / 4;
  for (int g = 0; g < 2; ++g) {
    const unsigned short* Wb = g ? Wb1 : Wb0;
    const float* a   = g ? a1 : a0;
    const float* val = g ? val1 : val0;
    const int* src   = g ? src1 : src0;
    const int* dst   = g ? dst1 : dst0;
    const int* rp_s  = rowptrs + (g * 2 + 0) * (V_N + 1);
    const int* rp_d  = rowptrs + (g * 2 + 1) * (V_N + 1);
    const int* ei_s  = eidx + (size_t)(g * 2 + 0) * E_N;
    const int* ei_d  = eidx + (size_t)(g * 2 + 1) * E_N;

    k_gather_H<<<VB, 256, 0, stream>>>(rp_s, ei_s, dst, val, Wb, a, Hb, s0, s1);
    k_fused_agg<<<VB, 256, 0, stream>>>(rp_d, ei_d, src, s0, s1, Hb, Hsum);
  }

  k_cvt_B<<<dim3(K_PAD / 64, HID / 64), 256, 0, stream>>>(Hsum, Bthi, Btlo);
  k_gemm1_mfma<<<dim3(M_ROWS / 64, 1, SK_MFMA), 512, 0, stream>>>(Xhi, Bthi, Btlo, fused);
  k_gemm2<<<M_ROWS, 256, 0, stream>>>(fused, fc_w, fc_b, out);
}

// Round 9
// 771.815 us; speedup vs baseline: 9.2474x; 1.0779x over previous
//
#include <hip/hip_runtime.h>
#include <hip/hip_bf16.h>
#include <cstddef>

#define V_N 30000
#define E_N 480000
#define HID 256
#define HEADS 4
#define HD 64
#define M_ROWS 1024   // 2*512
#define K_DIM 30000
#define K_PAD 30080   // 47 * 20 * 32
#define SK_MFMA 47
#define STEPS_Z 20
#define NR 8          // k_fill vertex ranges
#define NEG_SLOPE 0.2f
#define EPS_F 1e-9f

typedef __attribute__((ext_vector_type(8))) short bf16x8;
typedef __attribute__((ext_vector_type(4))) float f32x4;
typedef __attribute__((ext_vector_type(8))) unsigned short u16x8;
typedef __attribute__((ext_vector_type(4))) unsigned short u16x4;

__device__ inline unsigned short f2bf_rtn(float f) {
  unsigned u = __float_as_uint(f);
  unsigned r = u + 0x7fffu + ((u >> 16) & 1u);
  return (unsigned short)(r >> 16);
}
__device__ inline float bf2f(unsigned short h) {
  return __uint_as_float(((unsigned)h) << 16);
}

// ---------- CSR build: histogram ----------
__global__ __launch_bounds__(256) void k_hist(
    const int* __restrict__ s0g, const int* __restrict__ d0g,
    const int* __restrict__ s1g, const int* __restrict__ d1g,
    int* __restrict__ deg) {
  int e = blockIdx.x * 256 + threadIdx.x;
  if (e >= E_N) return;
  atomicAdd(&deg[0 * V_N + s0g[e]], 1);
  atomicAdd(&deg[1 * V_N + d0g[e]], 1);
  atomicAdd(&deg[2 * V_N + s1g[e]], 1);
  atomicAdd(&deg[3 * V_N + d1g[e]], 1);
}

// ---------- CSR build: 4 independent exclusive scans ----------
__global__ __launch_bounds__(1024) void k_scan4(
    const int* __restrict__ deg, int* __restrict__ rowptrs, int* __restrict__ cursors) {
  const int* dg = deg + blockIdx.x * V_N;
  int* rp = rowptrs + blockIdx.x * (V_N + 1);
  int* cur = cursors + blockIdx.x * V_N;
  __shared__ int part[1024];
  const int t = threadIdx.x;
  const int C = (V_N + 1023) / 1024;  // 30
  int base = t * C;
  int loc[C];
  int s = 0;
  #pragma unroll
  for (int i = 0; i < C; ++i) {
    int idx = base + i;
    int d = (idx < V_N) ? dg[idx] : 0;
    loc[i] = s;
    s += d;
  }
  part[t] = s;
  __syncthreads();
  for (int off = 1; off < 1024; off <<= 1) {
    int v_ = (t >= off) ? part[t - off] : 0;
    __syncthreads();
    part[t] += v_;
    __syncthreads();
  }
  int pre = (t == 0) ? 0 : part[t - 1];
  #pragma unroll
  for (int i = 0; i < C; ++i) {
    int idx = base + i;
    if (idx < V_N) {
      int v_ = pre + loc[i];
      rp[idx] = v_;
      cur[idx] = v_;
    }
  }
  if (t == 1023) rp[V_N] = part[1023];
}

// ---------- CSR build: fill, range-partitioned for L2-local writes ----------
__global__ __launch_bounds__(256) void k_fill(
    const int* __restrict__ s0g, const int* __restrict__ d0g,
    const int* __restrict__ s1g, const int* __restrict__ d1g,
    int* __restrict__ cursors, int* __restrict__ eidx) {
  int e = blockIdx.x * 256 + threadIdx.x;
  if (e >= E_N) return;
  const int v0 = blockIdx.y * (V_N / NR);
  const int v1 = v0 + (V_N / NR);
  int k, p;
  k = s0g[e];
  if (k >= v0 && k < v1) { p = atomicAdd(&cursors[0 * V_N + k], 1); eidx[0 * (size_t)E_N + p] = e; }
  k = d0g[e];
  if (k >= v0 && k < v1) { p = atomicAdd(&cursors[1 * V_N + k], 1); eidx[1 * (size_t)E_N + p] = e; }
  k = s1g[e];
  if (k >= v0 && k < v1) { p = atomicAdd(&cursors[2 * V_N + k], 1); eidx[2 * (size_t)E_N + p] = e; }
  k = d1g[e];
  if (k >= v0 && k < v1) { p = atomicAdd(&cursors[3 * V_N + k], 1); eidx[3 * (size_t)E_N + p] = e; }
}

// ---------- W -> bf16 ----------
__global__ __launch_bounds__(256) void k_cvt_W(
    const float* __restrict__ Wsrc, unsigned short* __restrict__ Wdst) {
  size_t i = ((size_t)blockIdx.x * 256 + threadIdx.x) * 8;
  const float4* p = reinterpret_cast<const float4*>(Wsrc + i);
  float4 x0 = p[0], x1 = p[1];
  float xs[8] = {x0.x, x0.y, x0.z, x0.w, x1.x, x1.y, x1.z, x1.w};
  u16x8 o;
  #pragma unroll
  for (int j = 0; j < 8; ++j) o[j] = f2bf_rtn(xs[j]);
  *reinterpret_cast<u16x8*>(Wdst + i) = o;
}

// ---------- Phase 1+2: H gather (bf16 W, 2-wide unroll) + score precompute ----------
__global__ __launch_bounds__(256) void k_gather_H(
    const int* __restrict__ rp, const int* __restrict__ eidx,
    const int* __restrict__ dst, const float* __restrict__ val,
    const unsigned short* __restrict__ Wb, const float* __restrict__ a,
    unsigned short* __restrict__ Hb, float* __restrict__ s0, float* __restrict__ s1) {
  int v = blockIdx.x * 4 + (threadIdx.x >> 6);
  if (v >= V_N) return;
  int lane = threadIdx.x & 63;
  int start = rp[v], end = rp[v + 1];
  const u16x4* W4 = reinterpret_cast<const u16x4*>(Wb);
  float4 acc = {0.f, 0.f, 0.f, 0.f};
  int da = 0, db = 0; float fa = 0.f, fb = 0.f;
  if (start < end)     { int e = eidx[start];     da = dst[e]; fa = val[e]; }
  if (start + 1 < end) { int e = eidx[start + 1]; db = dst[e]; fb = val[e]; }
  for (int i = start; i < end; i += 2) {
    int dc = 0, dd_ = 0; float fc = 0.f, fd = 0.f;
    if (i + 2 < end) { int e = eidx[i + 2]; dc  = dst[e]; fc = val[e]; }
    if (i + 3 < end) { int e = eidx[i + 3]; dd_ = dst[e]; fd = val[e]; }
    u16x4 wa = W4[(size_t)da * 64 + lane];
    u16x4 wb = W4[(size_t)db * 64 + lane];
    acc.x += fa * bf2f(wa[0]) + fb * bf2f(wb[0]);
    acc.y += fa * bf2f(wa[1]) + fb * bf2f(wb[1]);
    acc.z += fa * bf2f(wa[2]) + fb * bf2f(wb[2]);
    acc.w += fa * bf2f(wa[3]) + fb * bf2f(wb[3]);
    da = dc; fa = fc; db = dd_; fb = fd;
  }
  u16x4 hb;
  hb[0] = f2bf_rtn(acc.x); hb[1] = f2bf_rtn(acc.y);
  hb[2] = f2bf_rtn(acc.z); hb[3] = f2bf_rtn(acc.w);
  *(reinterpret_cast<u16x4*>(Hb) + (size_t)v * 64 + lane) = hb;
  int h = lane >> 4, dd = (lane & 15) * 4;
  const float* ah = a + h * (2 * HD);
  float p0 = acc.x * ah[dd] + acc.y * ah[dd + 1] + acc.z * ah[dd + 2] + acc.w * ah[dd + 3];
  float p1 = acc.x * ah[HD + dd] + acc.y * ah[HD + dd + 1] + acc.z * ah[HD + dd + 2] + acc.w * ah[HD + dd + 3];
  #pragma unroll
  for (int off = 1; off < 16; off <<= 1) {
    p0 += __shfl_xor(p0, off);
    p1 += __shfl_xor(p1, off);
  }
  if ((lane & 15) == 0) {
    s0[v * HEADS + h] = p0;
    s1[v * HEADS + h] = p1;
  }
}

// ---------- Phase 3+4: single-pass softmax + aggregation (2-wide unroll) ----------
__global__ __launch_bounds__(256) void k_fused_agg(
    const int* __restrict__ rp, const int* __restrict__ eidx,
    const int* __restrict__ src, const float* __restrict__ s0,
    const float* __restrict__ s1, const unsigned short* __restrict__ Hb,
    float* __restrict__ Hsum) {
  int v = blockIdx.x * 4 + (threadIdx.x >> 6);
  if (v >= V_N) return;
  int lane = threadIdx.x & 63;
  int start = rp[v], end = rp[v + 1];
  int hB = lane >> 4;
  float s1B = s1[v * HEADS + hB];
  const u16x4* H4 = reinterpret_cast<const u16x4*>(Hb);
  float4 acc = {0.f, 0.f, 0.f, 0.f};
  float dsum = 0.f;
  int sva = 0, svb = 0; float pa = -1e30f, pb = -1e30f;
  if (start < end)     { int e = eidx[start];     sva = src[e]; pa = s0[sva * HEADS + hB]; }
  if (start + 1 < end) { int e = eidx[start + 1]; svb = src[e]; pb = s0[svb * HEADS + hB]; }
  for (int i = start; i < end; i += 2) {
    int svc = 0, svd = 0; float pc = -1e30f, pd = -1e30f;
    if (i + 2 < end) { int e = eidx[i + 2]; svc = src[e]; pc = s0[svc * HEADS + hB]; }
    if (i + 3 < end) { int e = eidx[i + 3]; svd = src[e]; pd = s0[svd * HEADS + hB]; }
    u16x4 ha = H4[(size_t)sva * 64 + lane];
    u16x4 hbv = H4[(size_t)svb * 64 + lane];
    float sc0 = pa + s1B; sc0 = sc0 > 0.f ? sc0 : NEG_SLOPE * sc0;
    float sc1 = pb + s1B; sc1 = sc1 > 0.f ? sc1 : NEG_SLOPE * sc1;
    float ex0 = expf(sc0);
    float ex1 = expf(sc1);
    dsum += ex0 + ex1;
    acc.x += ex0 * bf2f(ha[0]) + ex1 * bf2f(hbv[0]);
    acc.y += ex0 * bf2f(ha[1]) + ex1 * bf2f(hbv[1]);
    acc.z += ex0 * bf2f(ha[2]) + ex1 * bf2f(hbv[2]);
    acc.w += ex0 * bf2f(ha[3]) + ex1 * bf2f(hbv[3]);
    sva = svc; pa = pc; svb = svd; pb = pd;
  }
  float inv = 1.f / (dsum + EPS_F);
  float4* o = reinterpret_cast<float4*>(Hsum) + (size_t)v * 64 + lane;
  float4 prev = *o;
  prev.x += acc.x * inv; prev.y += acc.y * inv;
  prev.z += acc.z * inv; prev.w += acc.w * inv;
  *o = prev;
}

// ---------- X -> bf16 (hi only), K padded to K_PAD ----------
__global__ __launch_bounds__(256) void k_cvt_X(
    const float* __restrict__ X, unsigned short* __restrict__ Xhi) {
  int row = blockIdx.y;
  int k0 = (blockIdx.x * 256 + threadIdx.x) * 8;
  if (k0 >= K_PAD) return;
  u16x8 hi;
  if (k0 < K_DIM) {
    const float4* p = reinterpret_cast<const float4*>(X + (size_t)row * K_DIM + k0);
    float4 x0 = p[0], x1 = p[1];
    float xs[8] = {x0.x, x0.y, x0.z, x0.w, x1.x, x1.y, x1.z, x1.w};
    #pragma unroll
    for (int j = 0; j < 8; ++j) hi[j] = f2bf_rtn(xs[j]);
  } else {
    #pragma unroll
    for (int j = 0; j < 8; ++j) hi[j] = 0;
  }
  *reinterpret_cast<u16x8*>(Xhi + (size_t)row * K_PAD + k0) = hi;
}

// ---------- Hsum -> transposed bf16 hi/lo split: Bt[h][k], K padded ----------
__global__ __launch_bounds__(256) void k_cvt_B(
    const float* __restrict__ Hs, unsigned short* __restrict__ Bthi,
    unsigned short* __restrict__ Btlo) {
  __shared__ float tile[64][65];
  const int t = threadIdx.x;
  const int v0 = blockIdx.x * 64;
  const int h0 = blockIdx.y * 64;
  #pragma unroll
  for (int i = 0; i < 16; ++i) {
    int vloc = (t >> 6) + i * 4;
    int v = v0 + vloc;
    float f = (v < V_N) ? Hs[(size_t)v * HID + h0 + (t & 63)] : 0.f;
    tile[vloc][t & 63] = f;
  }
  __syncthreads();
  #pragma unroll
  for (int j = 0; j < 16; ++j) {
    int hloc = (t >> 6) + j * 4;
    int vloc = t & 63;
    float f = tile[vloc][hloc];
    unsigned short h = f2bf_rtn(f);
    unsigned short l = f2bf_rtn(f - bf2f(h));
    size_t o = (size_t)(h0 + hloc) * K_PAD + v0 + vloc;
    Bthi[o] = h;
    Btlo[o] = l;
  }
}

// ---------- Big GEMM: fused += X @ Hsum; SK=47, 2-deep register pipeline ----------
__global__ __launch_bounds__(512) void k_gemm1_mfma(
    const unsigned short* __restrict__ Xhi,
    const unsigned short* __restrict__ Bthi, const unsigned short* __restrict__ Btlo,
    float* __restrict__ fused) {
  const int lane = threadIdx.x & 63;
  const int wave = threadIdx.x >> 6;   // 0..7
  const int mw = wave >> 2;            // 0..1
  const int nw = wave & 3;             // 0..3
  const int m0 = blockIdx.x * 64 + mw * 32;
  const int n0 = nw * 64;
  const int r = lane & 15;
  const int koff = (lane >> 4) * 8;
  const size_t kbase = (size_t)blockIdx.z * (STEPS_Z * 32) + koff;

  f32x4 acc[2][4] = {};
  const unsigned short* A0 = Xhi + (size_t)(m0 + r) * K_PAD + kbase;
  const unsigned short* A1 = Xhi + (size_t)(m0 + 16 + r) * K_PAD + kbase;
  const unsigned short* Bh[4];
  const unsigned short* Bl[4];
  #pragma unroll
  for (int j = 0; j < 4; ++j) {
    size_t o = (size_t)(n0 + 16 * j + r) * K_PAD + kbase;
    Bh[j] = Bthi + o;
    Bl[j] = Btlo + o;
  }
  bf16x8 a0 = *reinterpret_cast<const bf16x8*>(A0);
  bf16x8 a1 = *reinterpret_cast<const bf16x8*>(A1);
  bf16x8 bh[4], bl[4];
  #pragma unroll
  for (int j = 0; j < 4; ++j) {
    bh[j] = *reinterpret_cast<const bf16x8*>(Bh[j]);
    bl[j] = *reinterpret_cast<const bf16x8*>(Bl[j]);
  }
  for (int s = 0; s < STEPS_Z - 1; ++s) {
    const int nk = (s + 1) * 32;
    bf16x8 na0 = *reinterpret_cast<const bf16x8*>(A0 + nk);
    bf16x8 na1 = *reinterpret_cast<const bf16x8*>(A1 + nk);
    bf16x8 nbh[4], nbl[4];
    #pragma unroll
    for (int j = 0; j < 4; ++j) {
      nbh[j] = *reinterpret_cast<const bf16x8*>(Bh[j] + nk);
      nbl[j] = *reinterpret_cast<const bf16x8*>(Bl[j] + nk);
    }
    #pragma unroll
    for (int j = 0; j < 4; ++j) {
      acc[0][j] = __builtin_amdgcn_mfma_f32_16x16x32_bf16(a0, bh[j], acc[0][j], 0, 0, 0);
      acc[1][j] = __builtin_amdgcn_mfma_f32_16x16x32_bf16(a1, bh[j], acc[1][j], 0, 0, 0);
      acc[0][j] = __builtin_amdgcn_mfma_f32_16x16x32_bf16(a0, bl[j], acc[0][j], 0, 0, 0);
      acc[1][j] = __builtin_amdgcn_mfma_f32_16x16x32_bf16(a1, bl[j], acc[1][j], 0, 0, 0);
    }
    a0 = na0; a1 = na1;
    #pragma unroll
    for (int j = 0; j < 4; ++j) { bh[j] = nbh[j]; bl[j] = nbl[j]; }
  }
  #pragma unroll
  for (int j = 0; j < 4; ++j) {
    acc[0][j] = __builtin_amdgcn_mfma_f32_16x16x32_bf16(a0, bh[j], acc[0][j], 0, 0, 0);
    acc[1][j] = __builtin_amdgcn_mfma_f32_16x16x32_bf16(a1, bh[j], acc[1][j], 0, 0, 0);
    acc[0][j] = __builtin_amdgcn_mfma_f32_16x16x32_bf16(a0, bl[j], acc[0][j], 0, 0, 0);
    acc[1][j] = __builtin_amdgcn_mfma_f32_16x16x32_bf16(a1, bl[j], acc[1][j], 0, 0, 0);
  }
  const int rowoff = (lane >> 4) * 4;
  #pragma unroll
  for (int i = 0; i < 2; ++i) {
    int rowb = m0 + 16 * i + rowoff;
    #pragma unroll
    for (int j = 0; j < 4; ++j) {
      int colg = n0 + 16 * j + r;
      #pragma unroll
      for (int jj = 0; jj < 4; ++jj)
        unsafeAtomicAdd(&fused[(size_t)(rowb + jj) * HID + colg], acc[i][j][jj]);
    }
  }
}

// ---------- out = fused @ fc_w^T + fc_b ----------
__global__ __launch_bounds__(256) void k_gemm2(
    const float* __restrict__ fused, const float* __restrict__ fc_w,
    const float* __restrict__ fc_b, float* __restrict__ out) {
  int bd = blockIdx.x, o = threadIdx.x;
  __shared__ float fs[HID];
  fs[o] = fused[(size_t)bd * HID + o];
  __syncthreads();
  float acc = fc_b[o];
  const float* wr = fc_w + (size_t)o * HID;
  #pragma unroll 8
  for (int h = 0; h < HID; ++h) acc += fs[h] * wr[h];
  out[(size_t)bd * HID + o] = acc;
}

extern "C" void kernel_launch(void* const* d_in, const int* in_sizes, int n_in,
                              void* d_out, int out_size, void* d_ws, size_t ws_size,
                              hipStream_t stream) {
  const float* X    = (const float*)d_in[0];
  const float* W0   = (const float*)d_in[1];
  const float* a0   = (const float*)d_in[2];
  const float* W1   = (const float*)d_in[3];
  const float* a1   = (const float*)d_in[4];
  const float* fc_w = (const float*)d_in[5];
  const float* fc_b = (const float*)d_in[6];
  const float* val0 = (const float*)d_in[7];
  const float* val1 = (const float*)d_in[8];
  const int*   src0 = (const int*)d_in[9];
  const int*   dst0 = (const int*)d_in[10];
  const int*   src1 = (const int*)d_in[11];
  const int*   dst1 = (const int*)d_in[12];
  float* out = (float*)d_out;

  char* ws = (char*)d_ws;
  size_t off = 0;
  auto alloc = [&](size_t bytes) {
    void* p = ws + off;
    off += (bytes + 255) & ~(size_t)255;
    return p;
  };
  int*   deg     = (int*)alloc(4 * (size_t)V_N * 4);
  int*   rowptrs = (int*)alloc(4 * (size_t)(V_N + 1) * 4);
  int*   cursors = (int*)alloc(4 * (size_t)V_N * 4);
  int*   eidx    = (int*)alloc(4 * (size_t)E_N * 4);
  unsigned short* Hb  = (unsigned short*)alloc((size_t)V_N * HID * 2);
  unsigned short* Wb0 = (unsigned short*)alloc((size_t)V_N * HID * 2);
  unsigned short* Wb1 = (unsigned short*)alloc((size_t)V_N * HID * 2);
  float* Hsum    = (float*)alloc((size_t)V_N * HID * 4);
  float* s0      = (float*)alloc((size_t)V_N * HEADS * 4);
  float* s1      = (float*)alloc((size_t)V_N * HEADS * 4);
  float* fused   = (float*)alloc((size_t)M_ROWS * HID * 4);
  unsigned short* Xhi  = (unsigned short*)alloc((size_t)M_ROWS * K_PAD * 2);
  unsigned short* Bthi = (unsigned short*)alloc((size_t)HID * K_PAD * 2);
  unsigned short* Btlo = (unsigned short*)alloc((size_t)HID * K_PAD * 2);

  hipMemsetAsync(deg, 0, 4 * (size_t)V_N * 4, stream);
  hipMemsetAsync(Hsum, 0, (size_t)V_N * HID * 4, stream);
  hipMemsetAsync(fused, 0, (size_t)M_ROWS * HID * 4, stream);

  const int EB = (E_N + 255) / 256;
  k_hist<<<EB, 256, 0, stream>>>(src0, dst0, src1, dst1, deg);
  k_scan4<<<4, 1024, 0, stream>>>(deg, rowptrs, cursors);
  k_fill<<<dim3(EB, NR), 256, 0, stream>>>(src0, dst0, src1, dst1, cursors, eidx);

  const int WB = (int)(((size_t)V_N * HID / 8 + 255) / 256);  // 3750
  k_cvt_W<<<WB, 256, 0, stream>>>(W0, Wb0);
  k_cvt_W<<<WB, 256, 0, stream>>>(W1, Wb1);
  k_cvt_X<<<dim3(15, M_ROWS), 256, 0, stream>>>(X, Xhi);

  const int VB = (V_N + 3) / 4;
  for (int g = 0; g < 2; ++g) {
    const unsigned short* Wb = g ? Wb1 : Wb0;
    const float* a   = g ? a1 : a0;
    const float* val = g ? val1 : val0;
    const int* src   = g ? src1 : src0;
    const int* dst   = g ? dst1 : dst0;
    const int* rp_s  = rowptrs + (g * 2 + 0) * (V_N + 1);
    const int* rp_d  = rowptrs + (g * 2 + 1) * (V_N + 1);
    const int* ei_s  = eidx + (size_t)(g * 2 + 0) * E_N;
    const int* ei_d  = eidx + (size_t)(g * 2 + 1) * E_N;

    k_gather_H<<<VB, 256, 0, stream>>>(rp_s, ei_s, dst, val, Wb, a, Hb, s0, s1);
    k_fused_agg<<<VB, 256, 0, stream>>>(rp_d, ei_d, src, s0, s1, Hb, Hsum);
  }

  k_cvt_B<<<dim3(K_PAD / 64, HID / 64), 256, 0, stream>>>(Hsum, Bthi, Btlo);
  k_gemm1_mfma<<<dim3(M_ROWS / 64, 1, SK_MFMA), 512, 0, stream>>>(Xhi, Bthi, Btlo, fused);
  k_gemm2<<<M_ROWS, 256, 0, stream>>>(fused, fc_w, fc_b, out);
}

// Round 10
// 749.922 us; speedup vs baseline: 9.5174x; 1.0292x over previous
//
#include <hip/hip_runtime.h>
#include <hip/hip_bf16.h>
#include <cstddef>

#define V_N 30000
#define E_N 480000
#define HID 256
#define HEADS 4
#define HD 64
#define M_ROWS 1024   // 2*512
#define K_DIM 30000
#define K_PAD 30080   // 47 * 20 * 32
#define SK_MFMA 47
#define STEPS_Z 20
#define NR 8          // k_fill vertex ranges
#define NEG_SLOPE 0.2f
#define EPS_F 1e-9f

typedef __attribute__((ext_vector_type(8))) short bf16x8;
typedef __attribute__((ext_vector_type(4))) float f32x4;
typedef __attribute__((ext_vector_type(8))) unsigned short u16x8;
typedef __attribute__((ext_vector_type(4))) unsigned short u16x4;

__device__ inline unsigned short f2bf_rtn(float f) {
  unsigned u = __float_as_uint(f);
  unsigned r = u + 0x7fffu + ((u >> 16) & 1u);
  return (unsigned short)(r >> 16);
}
__device__ inline float bf2f(unsigned short h) {
  return __uint_as_float(((unsigned)h) << 16);
}

// ---------- CSR build: histogram ----------
__global__ __launch_bounds__(256) void k_hist(
    const int* __restrict__ s0g, const int* __restrict__ d0g,
    const int* __restrict__ s1g, const int* __restrict__ d1g,
    int* __restrict__ deg) {
  int e = blockIdx.x * 256 + threadIdx.x;
  if (e >= E_N) return;
  atomicAdd(&deg[0 * V_N + s0g[e]], 1);
  atomicAdd(&deg[1 * V_N + d0g[e]], 1);
  atomicAdd(&deg[2 * V_N + s1g[e]], 1);
  atomicAdd(&deg[3 * V_N + d1g[e]], 1);
}

// ---------- CSR build: 4 independent exclusive scans ----------
__global__ __launch_bounds__(1024) void k_scan4(
    const int* __restrict__ deg, int* __restrict__ rowptrs, int* __restrict__ cursors) {
  const int* dg = deg + blockIdx.x * V_N;
  int* rp = rowptrs + blockIdx.x * (V_N + 1);
  int* cur = cursors + blockIdx.x * V_N;
  __shared__ int part[1024];
  const int t = threadIdx.x;
  const int C = (V_N + 1023) / 1024;  // 30
  int base = t * C;
  int loc[C];
  int s = 0;
  #pragma unroll
  for (int i = 0; i < C; ++i) {
    int idx = base + i;
    int d = (idx < V_N) ? dg[idx] : 0;
    loc[i] = s;
    s += d;
  }
  part[t] = s;
  __syncthreads();
  for (int off = 1; off < 1024; off <<= 1) {
    int v_ = (t >= off) ? part[t - off] : 0;
    __syncthreads();
    part[t] += v_;
    __syncthreads();
  }
  int pre = (t == 0) ? 0 : part[t - 1];
  #pragma unroll
  for (int i = 0; i < C; ++i) {
    int idx = base + i;
    if (idx < V_N) {
      int v_ = pre + loc[i];
      rp[idx] = v_;
      cur[idx] = v_;
    }
  }
  if (t == 1023) rp[V_N] = part[1023];
}

// ---------- CSR build: fill, range-partitioned for L2-local writes ----------
__global__ __launch_bounds__(256) void k_fill(
    const int* __restrict__ s0g, const int* __restrict__ d0g,
    const int* __restrict__ s1g, const int* __restrict__ d1g,
    int* __restrict__ cursors, int* __restrict__ eidx) {
  int e = blockIdx.x * 256 + threadIdx.x;
  if (e >= E_N) return;
  const int v0 = blockIdx.y * (V_N / NR);
  const int v1 = v0 + (V_N / NR);
  int k, p;
  k = s0g[e];
  if (k >= v0 && k < v1) { p = atomicAdd(&cursors[0 * V_N + k], 1); eidx[0 * (size_t)E_N + p] = e; }
  k = d0g[e];
  if (k >= v0 && k < v1) { p = atomicAdd(&cursors[1 * V_N + k], 1); eidx[1 * (size_t)E_N + p] = e; }
  k = s1g[e];
  if (k >= v0 && k < v1) { p = atomicAdd(&cursors[2 * V_N + k], 1); eidx[2 * (size_t)E_N + p] = e; }
  k = d1g[e];
  if (k >= v0 && k < v1) { p = atomicAdd(&cursors[3 * V_N + k], 1); eidx[3 * (size_t)E_N + p] = e; }
}

// ---------- W -> bf16 ----------
__global__ __launch_bounds__(256) void k_cvt_W(
    const float* __restrict__ Wsrc, unsigned short* __restrict__ Wdst) {
  size_t i = ((size_t)blockIdx.x * 256 + threadIdx.x) * 8;
  const float4* p = reinterpret_cast<const float4*>(Wsrc + i);
  float4 x0 = p[0], x1 = p[1];
  float xs[8] = {x0.x, x0.y, x0.z, x0.w, x1.x, x1.y, x1.z, x1.w};
  u16x8 o;
  #pragma unroll
  for (int j = 0; j < 8; ++j) o[j] = f2bf_rtn(xs[j]);
  *reinterpret_cast<u16x8*>(Wdst + i) = o;
}

// ---------- Phase 1+2: H gather (bf16 W, 4-wide unroll) + score precompute ----------
__global__ __launch_bounds__(256) void k_gather_H(
    const int* __restrict__ rp, const int* __restrict__ eidx,
    const int* __restrict__ dst, const float* __restrict__ val,
    const unsigned short* __restrict__ Wb, const float* __restrict__ a,
    unsigned short* __restrict__ Hb, float* __restrict__ s0, float* __restrict__ s1) {
  int v = blockIdx.x * 4 + (threadIdx.x >> 6);
  if (v >= V_N) return;
  int lane = threadIdx.x & 63;
  int start = rp[v], end = rp[v + 1];
  const u16x4* W4 = reinterpret_cast<const u16x4*>(Wb);
  float4 acc = {0.f, 0.f, 0.f, 0.f};
  int dcur[4]; float fcur[4];
  #pragma unroll
  for (int q = 0; q < 4; ++q) {
    dcur[q] = 0; fcur[q] = 0.f;
    if (start + q < end) { int e = eidx[start + q]; dcur[q] = dst[e]; fcur[q] = val[e]; }
  }
  for (int i = start; i < end; i += 4) {
    int dnxt[4]; float fnxt[4];
    #pragma unroll
    for (int q = 0; q < 4; ++q) {
      dnxt[q] = 0; fnxt[q] = 0.f;
      if (i + 4 + q < end) { int e = eidx[i + 4 + q]; dnxt[q] = dst[e]; fnxt[q] = val[e]; }
    }
    u16x4 w0 = W4[(size_t)dcur[0] * 64 + lane];
    u16x4 w1 = W4[(size_t)dcur[1] * 64 + lane];
    u16x4 w2 = W4[(size_t)dcur[2] * 64 + lane];
    u16x4 w3 = W4[(size_t)dcur[3] * 64 + lane];
    acc.x += fcur[0] * bf2f(w0[0]) + fcur[1] * bf2f(w1[0]) + fcur[2] * bf2f(w2[0]) + fcur[3] * bf2f(w3[0]);
    acc.y += fcur[0] * bf2f(w0[1]) + fcur[1] * bf2f(w1[1]) + fcur[2] * bf2f(w2[1]) + fcur[3] * bf2f(w3[1]);
    acc.z += fcur[0] * bf2f(w0[2]) + fcur[1] * bf2f(w1[2]) + fcur[2] * bf2f(w2[2]) + fcur[3] * bf2f(w3[2]);
    acc.w += fcur[0] * bf2f(w0[3]) + fcur[1] * bf2f(w1[3]) + fcur[2] * bf2f(w2[3]) + fcur[3] * bf2f(w3[3]);
    #pragma unroll
    for (int q = 0; q < 4; ++q) { dcur[q] = dnxt[q]; fcur[q] = fnxt[q]; }
  }
  u16x4 hb;
  hb[0] = f2bf_rtn(acc.x); hb[1] = f2bf_rtn(acc.y);
  hb[2] = f2bf_rtn(acc.z); hb[3] = f2bf_rtn(acc.w);
  *(reinterpret_cast<u16x4*>(Hb) + (size_t)v * 64 + lane) = hb;
  int h = lane >> 4, dd = (lane & 15) * 4;
  const float* ah = a + h * (2 * HD);
  float p0 = acc.x * ah[dd] + acc.y * ah[dd + 1] + acc.z * ah[dd + 2] + acc.w * ah[dd + 3];
  float p1 = acc.x * ah[HD + dd] + acc.y * ah[HD + dd + 1] + acc.z * ah[HD + dd + 2] + acc.w * ah[HD + dd + 3];
  #pragma unroll
  for (int off = 1; off < 16; off <<= 1) {
    p0 += __shfl_xor(p0, off);
    p1 += __shfl_xor(p1, off);
  }
  if ((lane & 15) == 0) {
    s0[v * HEADS + h] = p0;
    s1[v * HEADS + h] = p1;
  }
}

// ---------- Phase 3+4: single-pass softmax + aggregation (4-wide unroll) ----------
__global__ __launch_bounds__(256) void k_fused_agg(
    const int* __restrict__ rp, const int* __restrict__ eidx,
    const int* __restrict__ src, const float* __restrict__ s0,
    const float* __restrict__ s1, const unsigned short* __restrict__ Hb,
    float* __restrict__ Hsum) {
  int v = blockIdx.x * 4 + (threadIdx.x >> 6);
  if (v >= V_N) return;
  int lane = threadIdx.x & 63;
  int start = rp[v], end = rp[v + 1];
  int hB = lane >> 4;
  float s1B = s1[v * HEADS + hB];
  const u16x4* H4 = reinterpret_cast<const u16x4*>(Hb);
  float4 acc = {0.f, 0.f, 0.f, 0.f};
  float dsum = 0.f;
  int svc[4]; float pc[4];
  #pragma unroll
  for (int q = 0; q < 4; ++q) {
    svc[q] = 0; pc[q] = -1e30f;
    if (start + q < end) { int e = eidx[start + q]; svc[q] = src[e]; pc[q] = s0[svc[q] * HEADS + hB]; }
  }
  for (int i = start; i < end; i += 4) {
    int svn[4]; float pn[4];
    #pragma unroll
    for (int q = 0; q < 4; ++q) {
      svn[q] = 0; pn[q] = -1e30f;
      if (i + 4 + q < end) { int e = eidx[i + 4 + q]; svn[q] = src[e]; pn[q] = s0[svn[q] * HEADS + hB]; }
    }
    u16x4 h0 = H4[(size_t)svc[0] * 64 + lane];
    u16x4 h1 = H4[(size_t)svc[1] * 64 + lane];
    u16x4 h2 = H4[(size_t)svc[2] * 64 + lane];
    u16x4 h3 = H4[(size_t)svc[3] * 64 + lane];
    float ex[4];
    #pragma unroll
    for (int q = 0; q < 4; ++q) {
      float sc = pc[q] + s1B;
      sc = sc > 0.f ? sc : NEG_SLOPE * sc;
      ex[q] = expf(sc);
      dsum += ex[q];
    }
    acc.x += ex[0] * bf2f(h0[0]) + ex[1] * bf2f(h1[0]) + ex[2] * bf2f(h2[0]) + ex[3] * bf2f(h3[0]);
    acc.y += ex[0] * bf2f(h0[1]) + ex[1] * bf2f(h1[1]) + ex[2] * bf2f(h2[1]) + ex[3] * bf2f(h3[1]);
    acc.z += ex[0] * bf2f(h0[2]) + ex[1] * bf2f(h1[2]) + ex[2] * bf2f(h2[2]) + ex[3] * bf2f(h3[2]);
    acc.w += ex[0] * bf2f(h0[3]) + ex[1] * bf2f(h1[3]) + ex[2] * bf2f(h2[3]) + ex[3] * bf2f(h3[3]);
    #pragma unroll
    for (int q = 0; q < 4; ++q) { svc[q] = svn[q]; pc[q] = pn[q]; }
  }
  float inv = 1.f / (dsum + EPS_F);
  float4* o = reinterpret_cast<float4*>(Hsum) + (size_t)v * 64 + lane;
  float4 prev = *o;
  prev.x += acc.x * inv; prev.y += acc.y * inv;
  prev.z += acc.z * inv; prev.w += acc.w * inv;
  *o = prev;
}

// ---------- X -> bf16 (hi only), K padded to K_PAD ----------
__global__ __launch_bounds__(256) void k_cvt_X(
    const float* __restrict__ X, unsigned short* __restrict__ Xhi) {
  int row = blockIdx.y;
  int k0 = (blockIdx.x * 256 + threadIdx.x) * 8;
  if (k0 >= K_PAD) return;
  u16x8 hi;
  if (k0 < K_DIM) {
    const float4* p = reinterpret_cast<const float4*>(X + (size_t)row * K_DIM + k0);
    float4 x0 = p[0], x1 = p[1];
    float xs[8] = {x0.x, x0.y, x0.z, x0.w, x1.x, x1.y, x1.z, x1.w};
    #pragma unroll
    for (int j = 0; j < 8; ++j) hi[j] = f2bf_rtn(xs[j]);
  } else {
    #pragma unroll
    for (int j = 0; j < 8; ++j) hi[j] = 0;
  }
  *reinterpret_cast<u16x8*>(Xhi + (size_t)row * K_PAD + k0) = hi;
}

// ---------- Hsum -> transposed bf16 hi/lo split: Bt[h][k], K padded ----------
__global__ __launch_bounds__(256) void k_cvt_B(
    const float* __restrict__ Hs, unsigned short* __restrict__ Bthi,
    unsigned short* __restrict__ Btlo) {
  __shared__ float tile[64][65];
  const int t = threadIdx.x;
  const int v0 = blockIdx.x * 64;
  const int h0 = blockIdx.y * 64;
  #pragma unroll
  for (int i = 0; i < 16; ++i) {
    int vloc = (t >> 6) + i * 4;
    int v = v0 + vloc;
    float f = (v < V_N) ? Hs[(size_t)v * HID + h0 + (t & 63)] : 0.f;
    tile[vloc][t & 63] = f;
  }
  __syncthreads();
  #pragma unroll
  for (int j = 0; j < 16; ++j) {
    int hloc = (t >> 6) + j * 4;
    int vloc = t & 63;
    float f = tile[vloc][hloc];
    unsigned short h = f2bf_rtn(f);
    unsigned short l = f2bf_rtn(f - bf2f(h));
    size_t o = (size_t)(h0 + hloc) * K_PAD + v0 + vloc;
    Bthi[o] = h;
    Btlo[o] = l;
  }
}

// ---------- Big GEMM: XCD-swizzled (each XCD owns contiguous z-range) ----------
__global__ __launch_bounds__(512) void k_gemm1_mfma(
    const unsigned short* __restrict__ Xhi,
    const unsigned short* __restrict__ Bthi, const unsigned short* __restrict__ Btlo,
    float* __restrict__ fused) {
  // 752 blocks = 8 XCDs x 94 slots; XCD k handles work ids [94k, 94k+94)
  // work id w -> z = w/16 (K-chunk), x = w%16 (M-block): each XCD sees ~6
  // consecutive z-chunks -> B panels stay in its private L2.
  const int bid = blockIdx.x;
  const int xcd = bid & 7;
  const int slot = bid >> 3;          // 0..93
  const int w = xcd * 94 + slot;      // bijective for 752 blocks
  const int zb = w >> 4;              // 0..46
  const int xb = w & 15;              // 0..15
  const int lane = threadIdx.x & 63;
  const int wave = threadIdx.x >> 6;   // 0..7
  const int mw = wave >> 2;            // 0..1
  const int nw = wave & 3;             // 0..3
  const int m0 = xb * 64 + mw * 32;
  const int n0 = nw * 64;
  const int r = lane & 15;
  const int koff = (lane >> 4) * 8;
  const size_t kbase = (size_t)zb * (STEPS_Z * 32) + koff;

  f32x4 acc[2][4] = {};
  const unsigned short* A0 = Xhi + (size_t)(m0 + r) * K_PAD + kbase;
  const unsigned short* A1 = Xhi + (size_t)(m0 + 16 + r) * K_PAD + kbase;
  const unsigned short* Bh[4];
  const unsigned short* Bl[4];
  #pragma unroll
  for (int j = 0; j < 4; ++j) {
    size_t o = (size_t)(n0 + 16 * j + r) * K_PAD + kbase;
    Bh[j] = Bthi + o;
    Bl[j] = Btlo + o;
  }
  bf16x8 a0 = *reinterpret_cast<const bf16x8*>(A0);
  bf16x8 a1 = *reinterpret_cast<const bf16x8*>(A1);
  bf16x8 bh[4], bl[4];
  #pragma unroll
  for (int j = 0; j < 4; ++j) {
    bh[j] = *reinterpret_cast<const bf16x8*>(Bh[j]);
    bl[j] = *reinterpret_cast<const bf16x8*>(Bl[j]);
  }
  for (int s = 0; s < STEPS_Z - 1; ++s) {
    const int nk = (s + 1) * 32;
    bf16x8 na0 = *reinterpret_cast<const bf16x8*>(A0 + nk);
    bf16x8 na1 = *reinterpret_cast<const bf16x8*>(A1 + nk);
    bf16x8 nbh[4], nbl[4];
    #pragma unroll
    for (int j = 0; j < 4; ++j) {
      nbh[j] = *reinterpret_cast<const bf16x8*>(Bh[j] + nk);
      nbl[j] = *reinterpret_cast<const bf16x8*>(Bl[j] + nk);
    }
    #pragma unroll
    for (int j = 0; j < 4; ++j) {
      acc[0][j] = __builtin_amdgcn_mfma_f32_16x16x32_bf16(a0, bh[j], acc[0][j], 0, 0, 0);
      acc[1][j] = __builtin_amdgcn_mfma_f32_16x16x32_bf16(a1, bh[j], acc[1][j], 0, 0, 0);
      acc[0][j] = __builtin_amdgcn_mfma_f32_16x16x32_bf16(a0, bl[j], acc[0][j], 0, 0, 0);
      acc[1][j] = __builtin_amdgcn_mfma_f32_16x16x32_bf16(a1, bl[j], acc[1][j], 0, 0, 0);
    }
    a0 = na0; a1 = na1;
    #pragma unroll
    for (int j = 0; j < 4; ++j) { bh[j] = nbh[j]; bl[j] = nbl[j]; }
  }
  #pragma unroll
  for (int j = 0; j < 4; ++j) {
    acc[0][j] = __builtin_amdgcn_mfma_f32_16x16x32_bf16(a0, bh[j], acc[0][j], 0, 0, 0);
    acc[1][j] = __builtin_amdgcn_mfma_f32_16x16x32_bf16(a1, bh[j], acc[1][j], 0, 0, 0);
    acc[0][j] = __builtin_amdgcn_mfma_f32_16x16x32_bf16(a0, bl[j], acc[0][j], 0, 0, 0);
    acc[1][j] = __builtin_amdgcn_mfma_f32_16x16x32_bf16(a1, bl[j], acc[1][j], 0, 0, 0);
  }
  const int rowoff = (lane >> 4) * 4;
  #pragma unroll
  for (int i = 0; i < 2; ++i) {
    int rowb = m0 + 16 * i + rowoff;
    #pragma unroll
    for (int j = 0; j < 4; ++j) {
      int colg = n0 + 16 * j + r;
      #pragma unroll
      for (int jj = 0; jj < 4; ++jj)
        unsafeAtomicAdd(&fused[(size_t)(rowb + jj) * HID + colg], acc[i][j][jj]);
    }
  }
}

// ---------- out = fused @ fc_w^T + fc_b ----------
__global__ __launch_bounds__(256) void k_gemm2(
    const float* __restrict__ fused, const float* __restrict__ fc_w,
    const float* __restrict__ fc_b, float* __restrict__ out) {
  int bd = blockIdx.x, o = threadIdx.x;
  __shared__ float fs[HID];
  fs[o] = fused[(size_t)bd * HID + o];
  __syncthreads();
  float acc = fc_b[o];
  const float* wr = fc_w + (size_t)o * HID;
  #pragma unroll 8
  for (int h = 0; h < HID; ++h) acc += fs[h] * wr[h];
  out[(size_t)bd * HID + o] = acc;
}

extern "C" void kernel_launch(void* const* d_in, const int* in_sizes, int n_in,
                              void* d_out, int out_size, void* d_ws, size_t ws_size,
                              hipStream_t stream) {
  const float* X    = (const float*)d_in[0];
  const float* W0   = (const float*)d_in[1];
  const float* a0   = (const float*)d_in[2];
  const float* W1   = (const float*)d_in[3];
  const float* a1   = (const float*)d_in[4];
  const float* fc_w = (const float*)d_in[5];
  const float* fc_b = (const float*)d_in[6];
  const float* val0 = (const float*)d_in[7];
  const float* val1 = (const float*)d_in[8];
  const int*   src0 = (const int*)d_in[9];
  const int*   dst0 = (const int*)d_in[10];
  const int*   src1 = (const int*)d_in[11];
  const int*   dst1 = (const int*)d_in[12];
  float* out = (float*)d_out;

  char* ws = (char*)d_ws;
  size_t off = 0;
  auto alloc = [&](size_t bytes) {
    void* p = ws + off;
    off += (bytes + 255) & ~(size_t)255;
    return p;
  };
  int*   deg     = (int*)alloc(4 * (size_t)V_N * 4);
  int*   rowptrs = (int*)alloc(4 * (size_t)(V_N + 1) * 4);
  int*   cursors = (int*)alloc(4 * (size_t)V_N * 4);
  int*   eidx    = (int*)alloc(4 * (size_t)E_N * 4);
  unsigned short* Hb  = (unsigned short*)alloc((size_t)V_N * HID * 2);
  unsigned short* Wb0 = (unsigned short*)alloc((size_t)V_N * HID * 2);
  unsigned short* Wb1 = (unsigned short*)alloc((size_t)V_N * HID * 2);
  float* Hsum    = (float*)alloc((size_t)V_N * HID * 4);
  float* s0      = (float*)alloc((size_t)V_N * HEADS * 4);
  float* s1      = (float*)alloc((size_t)V_N * HEADS * 4);
  float* fused   = (float*)alloc((size_t)M_ROWS * HID * 4);
  unsigned short* Xhi  = (unsigned short*)alloc((size_t)M_ROWS * K_PAD * 2);
  unsigned short* Bthi = (unsigned short*)alloc((size_t)HID * K_PAD * 2);
  unsigned short* Btlo = (unsigned short*)alloc((size_t)HID * K_PAD * 2);

  hipMemsetAsync(deg, 0, 4 * (size_t)V_N * 4, stream);
  hipMemsetAsync(Hsum, 0, (size_t)V_N * HID * 4, stream);
  hipMemsetAsync(fused, 0, (size_t)M_ROWS * HID * 4, stream);

  const int EB = (E_N + 255) / 256;
  k_hist<<<EB, 256, 0, stream>>>(src0, dst0, src1, dst1, deg);
  k_scan4<<<4, 1024, 0, stream>>>(deg, rowptrs, cursors);
  k_fill<<<dim3(EB, NR), 256, 0, stream>>>(src0, dst0, src1, dst1, cursors, eidx);

  const int WB = (int)(((size_t)V_N * HID / 8 + 255) / 256);  // 3750
  k_cvt_W<<<WB, 256, 0, stream>>>(W0, Wb0);
  k_cvt_W<<<WB, 256, 0, stream>>>(W1, Wb1);
  k_cvt_X<<<dim3(15, M_ROWS), 256, 0, stream>>>(X, Xhi);

  const int VB = (V_N + 3) / 4;
  for (int g = 0; g < 2; ++g) {
    const unsigned short* Wb = g ? Wb1 : Wb0;
    const float* a   = g ? a1 : a0;
    const float* val = g ? val1 : val0;
    const int* src   = g ? src1 : src0;
    const int* dst   = g ? dst1 : dst0;
    const int* rp_s  = rowptrs + (g * 2 + 0) * (V_N + 1);
    const int* rp_d  = rowptrs + (g * 2 + 1) * (V_N + 1);
    const int* ei_s  = eidx + (size_t)(g * 2 + 0) * E_N;
    const int* ei_d  = eidx + (size_t)(g * 2 + 1) * E_N;

    k_gather_H<<<VB, 256, 0, stream>>>(rp_s, ei_s, dst, val, Wb, a, Hb, s0, s1);
    k_fused_agg<<<VB, 256, 0, stream>>>(rp_d, ei_d, src, s0, s1, Hb, Hsum);
  }

  k_cvt_B<<<dim3(K_PAD / 64, HID / 64), 256, 0, stream>>>(Hsum, Bthi, Btlo);
  k_gemm1_mfma<<<8 * 94, 512, 0, stream>>>(Xhi, Bthi, Btlo, fused);
  k_gemm2<<<M_ROWS, 256, 0, stream>>>(fused, fc_w, fc_b, out);
}

// Round 11
// 667.243 us; speedup vs baseline: 10.6967x; 1.1239x over previous
//
#include <hip/hip_runtime.h>
#include <hip/hip_bf16.h>
#include <cstddef>

#define V_N 30000
#define E_N 480000
#define HID 256
#define HEADS 4
#define HD 64
#define M_ROWS 1024   // 2*512
#define K_DIM 30000
#define K_PAD 30080   // 47 * 640
#define CHUNK_EL 640  // K elements per GEMM block
#define NSTEP 10      // 640 / 64
#define NR 8          // k_fill vertex ranges
#define NEG_SLOPE 0.2f
#define EPS_F 1e-9f

typedef __attribute__((ext_vector_type(8))) short bf16x8;
typedef __attribute__((ext_vector_type(4))) float f32x4;
typedef __attribute__((ext_vector_type(8))) unsigned short u16x8;
typedef __attribute__((ext_vector_type(4))) unsigned short u16x4;

__device__ inline unsigned short f2bf_rtn(float f) {
  unsigned u = __float_as_uint(f);
  unsigned r = u + 0x7fffu + ((u >> 16) & 1u);
  return (unsigned short)(r >> 16);
}
__device__ inline float bf2f(unsigned short h) {
  return __uint_as_float(((unsigned)h) << 16);
}

__device__ __forceinline__ void gload_lds16(const void* g, void* l) {
  __builtin_amdgcn_global_load_lds(
      (const __attribute__((address_space(1))) void*)g,
      (__attribute__((address_space(3))) void*)l, 16, 0, 0);
}

// ---------- CSR build: histogram ----------
__global__ __launch_bounds__(256) void k_hist(
    const int* __restrict__ s0g, const int* __restrict__ d0g,
    const int* __restrict__ s1g, const int* __restrict__ d1g,
    int* __restrict__ deg) {
  int e = blockIdx.x * 256 + threadIdx.x;
  if (e >= E_N) return;
  atomicAdd(&deg[0 * V_N + s0g[e]], 1);
  atomicAdd(&deg[1 * V_N + d0g[e]], 1);
  atomicAdd(&deg[2 * V_N + s1g[e]], 1);
  atomicAdd(&deg[3 * V_N + d1g[e]], 1);
}

// ---------- CSR build: 4 independent exclusive scans ----------
__global__ __launch_bounds__(1024) void k_scan4(
    const int* __restrict__ deg, int* __restrict__ rowptrs, int* __restrict__ cursors) {
  const int* dg = deg + blockIdx.x * V_N;
  int* rp = rowptrs + blockIdx.x * (V_N + 1);
  int* cur = cursors + blockIdx.x * V_N;
  __shared__ int part[1024];
  const int t = threadIdx.x;
  const int C = (V_N + 1023) / 1024;  // 30
  int base = t * C;
  int loc[C];
  int s = 0;
  #pragma unroll
  for (int i = 0; i < C; ++i) {
    int idx = base + i;
    int d = (idx < V_N) ? dg[idx] : 0;
    loc[i] = s;
    s += d;
  }
  part[t] = s;
  __syncthreads();
  for (int off = 1; off < 1024; off <<= 1) {
    int v_ = (t >= off) ? part[t - off] : 0;
    __syncthreads();
    part[t] += v_;
    __syncthreads();
  }
  int pre = (t == 0) ? 0 : part[t - 1];
  #pragma unroll
  for (int i = 0; i < C; ++i) {
    int idx = base + i;
    if (idx < V_N) {
      int v_ = pre + loc[i];
      rp[idx] = v_;
      cur[idx] = v_;
    }
  }
  if (t == 1023) rp[V_N] = part[1023];
}

// ---------- CSR build: fill payload CSR, range-partitioned ----------
__global__ __launch_bounds__(256) void k_fill(
    const int* __restrict__ s0g, const int* __restrict__ d0g,
    const int* __restrict__ s1g, const int* __restrict__ d1g,
    const float* __restrict__ val0, const float* __restrict__ val1,
    int* __restrict__ cursors, int2* __restrict__ csr_s, int* __restrict__ csr_d) {
  int e = blockIdx.x * 256 + threadIdx.x;
  if (e >= E_N) return;
  const int v0 = blockIdx.y * (V_N / NR);
  const int v1 = v0 + (V_N / NR);
  int k, p;
  k = s0g[e];
  if (k >= v0 && k < v1) {
    p = atomicAdd(&cursors[0 * V_N + k], 1);
    csr_s[p] = make_int2(d0g[e], __float_as_int(val0[e]));
  }
  k = d0g[e];
  if (k >= v0 && k < v1) {
    p = atomicAdd(&cursors[1 * V_N + k], 1);
    csr_d[p] = s0g[e];
  }
  k = s1g[e];
  if (k >= v0 && k < v1) {
    p = atomicAdd(&cursors[2 * V_N + k], 1);
    csr_s[(size_t)E_N + p] = make_int2(d1g[e], __float_as_int(val1[e]));
  }
  k = d1g[e];
  if (k >= v0 && k < v1) {
    p = atomicAdd(&cursors[3 * V_N + k], 1);
    csr_d[(size_t)E_N + p] = s1g[e];
  }
}

// ---------- W -> bf16 ----------
__global__ __launch_bounds__(256) void k_cvt_W(
    const float* __restrict__ Wsrc, unsigned short* __restrict__ Wdst) {
  size_t i = ((size_t)blockIdx.x * 256 + threadIdx.x) * 8;
  const float4* p = reinterpret_cast<const float4*>(Wsrc + i);
  float4 x0 = p[0], x1 = p[1];
  float xs[8] = {x0.x, x0.y, x0.z, x0.w, x1.x, x1.y, x1.z, x1.w};
  u16x8 o;
  #pragma unroll
  for (int j = 0; j < 8; ++j) o[j] = f2bf_rtn(xs[j]);
  *reinterpret_cast<u16x8*>(Wdst + i) = o;
}

// ---------- Phase 1+2: H gather (payload CSR, 4-wide) + score precompute ----------
__global__ __launch_bounds__(256) void k_gather_H(
    const int* __restrict__ rp, const int2* __restrict__ csr,
    const unsigned short* __restrict__ Wb, const float* __restrict__ a,
    unsigned short* __restrict__ Hb, float* __restrict__ s0, float* __restrict__ s1) {
  int v = blockIdx.x * 4 + (threadIdx.x >> 6);
  if (v >= V_N) return;
  int lane = threadIdx.x & 63;
  int start = rp[v], end = rp[v + 1];
  const u16x4* W4 = reinterpret_cast<const u16x4*>(Wb);
  float4 acc = {0.f, 0.f, 0.f, 0.f};
  int dcur[4]; float fcur[4];
  #pragma unroll
  for (int q = 0; q < 4; ++q) {
    dcur[q] = 0; fcur[q] = 0.f;
    if (start + q < end) { int2 pl = csr[start + q]; dcur[q] = pl.x; fcur[q] = __int_as_float(pl.y); }
  }
  for (int i = start; i < end; i += 4) {
    int dnxt[4]; float fnxt[4];
    #pragma unroll
    for (int q = 0; q < 4; ++q) {
      dnxt[q] = 0; fnxt[q] = 0.f;
      if (i + 4 + q < end) { int2 pl = csr[i + 4 + q]; dnxt[q] = pl.x; fnxt[q] = __int_as_float(pl.y); }
    }
    u16x4 w0 = W4[(size_t)dcur[0] * 64 + lane];
    u16x4 w1 = W4[(size_t)dcur[1] * 64 + lane];
    u16x4 w2 = W4[(size_t)dcur[2] * 64 + lane];
    u16x4 w3 = W4[(size_t)dcur[3] * 64 + lane];
    acc.x += fcur[0] * bf2f(w0[0]) + fcur[1] * bf2f(w1[0]) + fcur[2] * bf2f(w2[0]) + fcur[3] * bf2f(w3[0]);
    acc.y += fcur[0] * bf2f(w0[1]) + fcur[1] * bf2f(w1[1]) + fcur[2] * bf2f(w2[1]) + fcur[3] * bf2f(w3[1]);
    acc.z += fcur[0] * bf2f(w0[2]) + fcur[1] * bf2f(w1[2]) + fcur[2] * bf2f(w2[2]) + fcur[3] * bf2f(w3[2]);
    acc.w += fcur[0] * bf2f(w0[3]) + fcur[1] * bf2f(w1[3]) + fcur[2] * bf2f(w2[3]) + fcur[3] * bf2f(w3[3]);
    #pragma unroll
    for (int q = 0; q < 4; ++q) { dcur[q] = dnxt[q]; fcur[q] = fnxt[q]; }
  }
  u16x4 hb;
  hb[0] = f2bf_rtn(acc.x); hb[1] = f2bf_rtn(acc.y);
  hb[2] = f2bf_rtn(acc.z); hb[3] = f2bf_rtn(acc.w);
  *(reinterpret_cast<u16x4*>(Hb) + (size_t)v * 64 + lane) = hb;
  int h = lane >> 4, dd = (lane & 15) * 4;
  const float* ah = a + h * (2 * HD);
  float p0 = acc.x * ah[dd] + acc.y * ah[dd + 1] + acc.z * ah[dd + 2] + acc.w * ah[dd + 3];
  float p1 = acc.x * ah[HD + dd] + acc.y * ah[HD + dd + 1] + acc.z * ah[HD + dd + 2] + acc.w * ah[HD + dd + 3];
  #pragma unroll
  for (int off = 1; off < 16; off <<= 1) {
    p0 += __shfl_xor(p0, off);
    p1 += __shfl_xor(p1, off);
  }
  if ((lane & 15) == 0) {
    s0[v * HEADS + h] = p0;
    s1[v * HEADS + h] = p1;
  }
}

// ---------- Phase 3+4: single-pass softmax + aggregation (payload CSR, 4-wide) ----------
__global__ __launch_bounds__(256) void k_fused_agg(
    const int* __restrict__ rp, const int* __restrict__ csr,
    const float* __restrict__ s0, const float* __restrict__ s1,
    const unsigned short* __restrict__ Hb, float* __restrict__ Hsum) {
  int v = blockIdx.x * 4 + (threadIdx.x >> 6);
  if (v >= V_N) return;
  int lane = threadIdx.x & 63;
  int start = rp[v], end = rp[v + 1];
  int hB = lane >> 4;
  float s1B = s1[v * HEADS + hB];
  const u16x4* H4 = reinterpret_cast<const u16x4*>(Hb);
  float4 acc = {0.f, 0.f, 0.f, 0.f};
  float dsum = 0.f;
  int svc[4]; float pc[4];
  #pragma unroll
  for (int q = 0; q < 4; ++q) {
    svc[q] = 0; pc[q] = -1e30f;
    if (start + q < end) { svc[q] = csr[start + q]; pc[q] = s0[svc[q] * HEADS + hB]; }
  }
  for (int i = start; i < end; i += 4) {
    int svn[4]; float pn[4];
    #pragma unroll
    for (int q = 0; q < 4; ++q) {
      svn[q] = 0; pn[q] = -1e30f;
      if (i + 4 + q < end) { svn[q] = csr[i + 4 + q]; pn[q] = s0[svn[q] * HEADS + hB]; }
    }
    u16x4 h0 = H4[(size_t)svc[0] * 64 + lane];
    u16x4 h1 = H4[(size_t)svc[1] * 64 + lane];
    u16x4 h2 = H4[(size_t)svc[2] * 64 + lane];
    u16x4 h3 = H4[(size_t)svc[3] * 64 + lane];
    float ex[4];
    #pragma unroll
    for (int q = 0; q < 4; ++q) {
      float sc = pc[q] + s1B;
      sc = sc > 0.f ? sc : NEG_SLOPE * sc;
      ex[q] = expf(sc);
      dsum += ex[q];
    }
    acc.x += ex[0] * bf2f(h0[0]) + ex[1] * bf2f(h1[0]) + ex[2] * bf2f(h2[0]) + ex[3] * bf2f(h3[0]);
    acc.y += ex[0] * bf2f(h0[1]) + ex[1] * bf2f(h1[1]) + ex[2] * bf2f(h2[1]) + ex[3] * bf2f(h3[1]);
    acc.z += ex[0] * bf2f(h0[2]) + ex[1] * bf2f(h1[2]) + ex[2] * bf2f(h2[2]) + ex[3] * bf2f(h3[2]);
    acc.w += ex[0] * bf2f(h0[3]) + ex[1] * bf2f(h1[3]) + ex[2] * bf2f(h2[3]) + ex[3] * bf2f(h3[3]);
    #pragma unroll
    for (int q = 0; q < 4; ++q) { svc[q] = svn[q]; pc[q] = pn[q]; }
  }
  float inv = 1.f / (dsum + EPS_F);
  float4* o = reinterpret_cast<float4*>(Hsum) + (size_t)v * 64 + lane;
  float4 prev = *o;
  prev.x += acc.x * inv; prev.y += acc.y * inv;
  prev.z += acc.z * inv; prev.w += acc.w * inv;
  *o = prev;
}

// ---------- X -> bf16, granule-XOR-swizzled within each 128B block ----------
// granule = 8 bf16 = 16B; store granule g at position (g&~7)|((g&7)^(row&7)).
// GEMM stages rows linearly via global_load_lds and ds_reads with the same XOR.
__global__ __launch_bounds__(256) void k_cvt_X(
    const float* __restrict__ X, unsigned short* __restrict__ Xhi) {
  int row = blockIdx.y;
  int g = blockIdx.x * 256 + threadIdx.x;
  if (g >= K_PAD / 8) return;
  int k0 = g * 8;
  u16x8 hi;
  if (k0 < K_DIM) {
    const float4* p = reinterpret_cast<const float4*>(X + (size_t)row * K_DIM + k0);
    float4 x0 = p[0], x1 = p[1];
    float xs[8] = {x0.x, x0.y, x0.z, x0.w, x1.x, x1.y, x1.z, x1.w};
    #pragma unroll
    for (int j = 0; j < 8; ++j) hi[j] = f2bf_rtn(xs[j]);
  } else {
    #pragma unroll
    for (int j = 0; j < 8; ++j) hi[j] = 0;
  }
  int gs = (g & ~7) | ((g & 7) ^ (row & 7));
  *reinterpret_cast<u16x8*>(Xhi + (size_t)row * K_PAD + gs * 8) = hi;
}

// ---------- Hsum -> transposed bf16 hi/lo split: Bt[h][k], K padded ----------
__global__ __launch_bounds__(256) void k_cvt_B(
    const float* __restrict__ Hs, unsigned short* __restrict__ Bthi,
    unsigned short* __restrict__ Btlo) {
  __shared__ float tile[64][65];
  const int t = threadIdx.x;
  const int v0 = blockIdx.x * 64;
  const int h0 = blockIdx.y * 64;
  #pragma unroll
  for (int i = 0; i < 16; ++i) {
    int vloc = (t >> 6) + i * 4;
    int v = v0 + vloc;
    float f = (v < V_N) ? Hs[(size_t)v * HID + h0 + (t & 63)] : 0.f;
    tile[vloc][t & 63] = f;
  }
  __syncthreads();
  #pragma unroll
  for (int j = 0; j < 16; ++j) {
    int hloc = (t >> 6) + j * 4;
    int vloc = t & 63;
    float f = tile[vloc][hloc];
    unsigned short h = f2bf_rtn(f);
    unsigned short l = f2bf_rtn(f - bf2f(h));
    size_t o = (size_t)(h0 + hloc) * K_PAD + v0 + vloc;
    Bthi[o] = h;
    Btlo[o] = l;
  }
}

// ---------- Big GEMM: LDS-staged A (global_load_lds, dbuf) + direct B, XCD swizzle ----------
__global__ __launch_bounds__(512) void k_gemm1_mfma(
    const unsigned short* __restrict__ Xhi,
    const unsigned short* __restrict__ Bthi, const unsigned short* __restrict__ Btlo,
    float* __restrict__ fused) {
  __shared__ __align__(16) unsigned short Asm[2][64 * 64];  // 2 x 8KB, [row][64 el]
  const int bid = blockIdx.x;
  const int xcd = bid & 7;
  const int slot = bid >> 3;
  const int w = xcd * 94 + slot;       // bijective for 752
  const int zb = w >> 4;               // 0..46 K-chunk
  const int xb = w & 15;               // 0..15 M-block
  const int lane = threadIdx.x & 63;
  const int wave = threadIdx.x >> 6;   // 0..7
  const int mw = wave >> 2;            // 0..1
  const int nw = wave & 3;             // 0..3
  const int m0 = xb * 64;
  const int n0 = nw * 64;
  const int r = lane & 15;
  const int koff = lane >> 4;          // 0..3
  const int kel0 = zb * CHUNK_EL;

  // staging: each wave issues 1 x 1KB global_load_lds per step (rows wave*8..+8, 128B/row)
  const int srow = wave * 8 + (lane >> 3);
  const unsigned short* gsrc = Xhi + (size_t)(m0 + srow) * K_PAD + kel0 + (lane & 7) * 8;
  unsigned short* lb0 = &Asm[0][wave * 8 * 64];
  unsigned short* lb1 = &Asm[1][wave * 8 * 64];

  f32x4 acc[2][4] = {};
  const unsigned short* Bh[4];
  const unsigned short* Bl[4];
  #pragma unroll
  for (int j = 0; j < 4; ++j) {
    size_t o = (size_t)(n0 + 16 * j + r) * K_PAD + kel0 + koff * 8;
    Bh[j] = Bthi + o;
    Bl[j] = Btlo + o;
  }
  const int xr = r & 7;  // rows mw*32+i*16+r have row&7 == r&7
  const int arow0 = (mw * 32 + r) * 64;
  const int arow1 = (mw * 32 + 16 + r) * 64;

  gload_lds16(gsrc, lb0);
  __syncthreads();

  for (int t = 0; t < NSTEP; ++t) {
    const unsigned short* curbuf = (t & 1) ? Asm[1] : Asm[0];
    if (t + 1 < NSTEP)
      gload_lds16(gsrc + (t + 1) * 64, (t & 1) ? lb0 : lb1);
    const int toff = t * 64;
    #pragma unroll
    for (int kk = 0; kk < 2; ++kk) {
      bf16x8 bh[4], bl[4];
      #pragma unroll
      for (int j = 0; j < 4; ++j) {
        bh[j] = *reinterpret_cast<const bf16x8*>(Bh[j] + toff + kk * 32);
        bl[j] = *reinterpret_cast<const bf16x8*>(Bl[j] + toff + kk * 32);
      }
      const int gr = ((kk * 4 + koff) ^ xr) * 8;
      bf16x8 a0 = *reinterpret_cast<const bf16x8*>(&curbuf[arow0 + gr]);
      bf16x8 a1 = *reinterpret_cast<const bf16x8*>(&curbuf[arow1 + gr]);
      #pragma unroll
      for (int j = 0; j < 4; ++j) {
        acc[0][j] = __builtin_amdgcn_mfma_f32_16x16x32_bf16(a0, bh[j], acc[0][j], 0, 0, 0);
        acc[1][j] = __builtin_amdgcn_mfma_f32_16x16x32_bf16(a1, bh[j], acc[1][j], 0, 0, 0);
        acc[0][j] = __builtin_amdgcn_mfma_f32_16x16x32_bf16(a0, bl[j], acc[0][j], 0, 0, 0);
        acc[1][j] = __builtin_amdgcn_mfma_f32_16x16x32_bf16(a1, bl[j], acc[1][j], 0, 0, 0);
      }
    }
    __syncthreads();
  }
  const int rowoff = koff * 4;
  #pragma unroll
  for (int i = 0; i < 2; ++i) {
    int rowb = m0 + mw * 32 + 16 * i + rowoff;
    #pragma unroll
    for (int j = 0; j < 4; ++j) {
      int colg = n0 + 16 * j + r;
      #pragma unroll
      for (int jj = 0; jj < 4; ++jj)
        unsafeAtomicAdd(&fused[(size_t)(rowb + jj) * HID + colg], acc[i][j][jj]);
    }
  }
}

// ---------- out = fused @ fc_w^T + fc_b ----------
__global__ __launch_bounds__(256) void k_gemm2(
    const float* __restrict__ fused, const float* __restrict__ fc_w,
    const float* __restrict__ fc_b, float* __restrict__ out) {
  int bd = blockIdx.x, o = threadIdx.x;
  __shared__ float fs[HID];
  fs[o] = fused[(size_t)bd * HID + o];
  __syncthreads();
  float acc = fc_b[o];
  const float* wr = fc_w + (size_t)o * HID;
  #pragma unroll 8
  for (int h = 0; h < HID; ++h) acc += fs[h] * wr[h];
  out[(size_t)bd * HID + o] = acc;
}

extern "C" void kernel_launch(void* const* d_in, const int* in_sizes, int n_in,
                              void* d_out, int out_size, void* d_ws, size_t ws_size,
                              hipStream_t stream) {
  const float* X    = (const float*)d_in[0];
  const float* W0   = (const float*)d_in[1];
  const float* a0   = (const float*)d_in[2];
  const float* W1   = (const float*)d_in[3];
  const float* a1   = (const float*)d_in[4];
  const float* fc_w = (const float*)d_in[5];
  const float* fc_b = (const float*)d_in[6];
  const float* val0 = (const float*)d_in[7];
  const float* val1 = (const float*)d_in[8];
  const int*   src0 = (const int*)d_in[9];
  const int*   dst0 = (const int*)d_in[10];
  const int*   src1 = (const int*)d_in[11];
  const int*   dst1 = (const int*)d_in[12];
  float* out = (float*)d_out;

  char* ws = (char*)d_ws;
  size_t off = 0;
  auto alloc = [&](size_t bytes) {
    void* p = ws + off;
    off += (bytes + 255) & ~(size_t)255;
    return p;
  };
  int*   deg     = (int*)alloc(4 * (size_t)V_N * 4);
  int*   rowptrs = (int*)alloc(4 * (size_t)(V_N + 1) * 4);
  int*   cursors = (int*)alloc(4 * (size_t)V_N * 4);
  int2*  csr_s   = (int2*)alloc(2 * (size_t)E_N * 8);
  int*   csr_d   = (int*)alloc(2 * (size_t)E_N * 4);
  unsigned short* Hb  = (unsigned short*)alloc((size_t)V_N * HID * 2);
  unsigned short* Wb0 = (unsigned short*)alloc((size_t)V_N * HID * 2);
  unsigned short* Wb1 = (unsigned short*)alloc((size_t)V_N * HID * 2);
  float* Hsum    = (float*)alloc((size_t)V_N * HID * 4);
  float* s0      = (float*)alloc((size_t)V_N * HEADS * 4);
  float* s1      = (float*)alloc((size_t)V_N * HEADS * 4);
  float* fused   = (float*)alloc((size_t)M_ROWS * HID * 4);
  unsigned short* Xhi  = (unsigned short*)alloc((size_t)M_ROWS * K_PAD * 2);
  unsigned short* Bthi = (unsigned short*)alloc((size_t)HID * K_PAD * 2);
  unsigned short* Btlo = (unsigned short*)alloc((size_t)HID * K_PAD * 2);

  hipMemsetAsync(deg, 0, 4 * (size_t)V_N * 4, stream);
  hipMemsetAsync(Hsum, 0, (size_t)V_N * HID * 4, stream);
  hipMemsetAsync(fused, 0, (size_t)M_ROWS * HID * 4, stream);

  const int EB = (E_N + 255) / 256;
  k_hist<<<EB, 256, 0, stream>>>(src0, dst0, src1, dst1, deg);
  k_scan4<<<4, 1024, 0, stream>>>(deg, rowptrs, cursors);
  k_fill<<<dim3(EB, NR), 256, 0, stream>>>(src0, dst0, src1, dst1, val0, val1,
                                           cursors, csr_s, csr_d);

  const int WB = (int)(((size_t)V_N * HID / 8 + 255) / 256);  // 3750
  k_cvt_W<<<WB, 256, 0, stream>>>(W0, Wb0);
  k_cvt_W<<<WB, 256, 0, stream>>>(W1, Wb1);
  k_cvt_X<<<dim3(15, M_ROWS), 256, 0, stream>>>(X, Xhi);

  const int VB = (V_N + 3) / 4;
  for (int g = 0; g < 2; ++g) {
    const unsigned short* Wb = g ? Wb1 : Wb0;
    const float* a  = g ? a1 : a0;
    const int* rp_s = rowptrs + (g * 2 + 0) * (V_N + 1);
    const int* rp_d = rowptrs + (g * 2 + 1) * (V_N + 1);
    const int2* cs  = csr_s + (size_t)g * E_N;
    const int*  cd  = csr_d + (size_t)g * E_N;

    k_gather_H<<<VB, 256, 0, stream>>>(rp_s, cs, Wb, a, Hb, s0, s1);
    k_fused_agg<<<VB, 256, 0, stream>>>(rp_d, cd, s0, s1, Hb, Hsum);
  }

  k_cvt_B<<<dim3(K_PAD / 64, HID / 64), 256, 0, stream>>>(Hsum, Bthi, Btlo);
  k_gemm1_mfma<<<8 * 94, 512, 0, stream>>>(Xhi, Bthi, Btlo, fused);
  k_gemm2<<<M_ROWS, 256, 0, stream>>>(fused, fc_w, fc_b, out);
}

// Round 12
// 664.675 us; speedup vs baseline: 10.7380x; 1.0039x over previous
//
#include <hip/hip_runtime.h>
#include <hip/hip_bf16.h>
#include <cstddef>

#define V_N 30000
#define E_N 480000
#define HID 256
#define HEADS 4
#define HD 64
#define M_ROWS 1024   // 2*512
#define K_DIM 30000
#define K_PAD 30080   // 47 * 640
#define CHUNK_EL 640  // K elements per GEMM block
#define NSTEP 10      // 640 / 64
#define SK_MFMA 47
#define NR 8          // k_fill vertex ranges
#define NEG_SLOPE 0.2f
#define EPS_F 1e-9f

typedef __attribute__((ext_vector_type(8))) short bf16x8;
typedef __attribute__((ext_vector_type(4))) float f32x4;
typedef __attribute__((ext_vector_type(8))) unsigned short u16x8;
typedef __attribute__((ext_vector_type(4))) unsigned short u16x4;

__device__ inline unsigned short f2bf_rtn(float f) {
  unsigned u = __float_as_uint(f);
  unsigned r = u + 0x7fffu + ((u >> 16) & 1u);
  return (unsigned short)(r >> 16);
}
__device__ inline float bf2f(unsigned short h) {
  return __uint_as_float(((unsigned)h) << 16);
}

__device__ __forceinline__ void gload_lds16(const void* g, void* l) {
  __builtin_amdgcn_global_load_lds(
      (const __attribute__((address_space(1))) void*)g,
      (__attribute__((address_space(3))) void*)l, 16, 0, 0);
}

// ---------- CSR build: histogram ----------
__global__ __launch_bounds__(256) void k_hist(
    const int* __restrict__ s0g, const int* __restrict__ d0g,
    const int* __restrict__ s1g, const int* __restrict__ d1g,
    int* __restrict__ deg) {
  int e = blockIdx.x * 256 + threadIdx.x;
  if (e >= E_N) return;
  atomicAdd(&deg[0 * V_N + s0g[e]], 1);
  atomicAdd(&deg[1 * V_N + d0g[e]], 1);
  atomicAdd(&deg[2 * V_N + s1g[e]], 1);
  atomicAdd(&deg[3 * V_N + d1g[e]], 1);
}

// ---------- CSR build: 4 independent exclusive scans ----------
__global__ __launch_bounds__(1024) void k_scan4(
    const int* __restrict__ deg, int* __restrict__ rowptrs, int* __restrict__ cursors) {
  const int* dg = deg + blockIdx.x * V_N;
  int* rp = rowptrs + blockIdx.x * (V_N + 1);
  int* cur = cursors + blockIdx.x * V_N;
  __shared__ int part[1024];
  const int t = threadIdx.x;
  const int C = (V_N + 1023) / 1024;  // 30
  int base = t * C;
  int loc[C];
  int s = 0;
  #pragma unroll
  for (int i = 0; i < C; ++i) {
    int idx = base + i;
    int d = (idx < V_N) ? dg[idx] : 0;
    loc[i] = s;
    s += d;
  }
  part[t] = s;
  __syncthreads();
  for (int off = 1; off < 1024; off <<= 1) {
    int v_ = (t >= off) ? part[t - off] : 0;
    __syncthreads();
    part[t] += v_;
    __syncthreads();
  }
  int pre = (t == 0) ? 0 : part[t - 1];
  #pragma unroll
  for (int i = 0; i < C; ++i) {
    int idx = base + i;
    if (idx < V_N) {
      int v_ = pre + loc[i];
      rp[idx] = v_;
      cur[idx] = v_;
    }
  }
  if (t == 1023) rp[V_N] = part[1023];
}

// ---------- CSR build: fill payload CSR, range-partitioned ----------
__global__ __launch_bounds__(256) void k_fill(
    const int* __restrict__ s0g, const int* __restrict__ d0g,
    const int* __restrict__ s1g, const int* __restrict__ d1g,
    const float* __restrict__ val0, const float* __restrict__ val1,
    int* __restrict__ cursors, int2* __restrict__ csr_s, int* __restrict__ csr_d) {
  int e = blockIdx.x * 256 + threadIdx.x;
  if (e >= E_N) return;
  const int v0 = blockIdx.y * (V_N / NR);
  const int v1 = v0 + (V_N / NR);
  int k, p;
  k = s0g[e];
  if (k >= v0 && k < v1) {
    p = atomicAdd(&cursors[0 * V_N + k], 1);
    csr_s[p] = make_int2(d0g[e], __float_as_int(val0[e]));
  }
  k = d0g[e];
  if (k >= v0 && k < v1) {
    p = atomicAdd(&cursors[1 * V_N + k], 1);
    csr_d[p] = s0g[e];
  }
  k = s1g[e];
  if (k >= v0 && k < v1) {
    p = atomicAdd(&cursors[2 * V_N + k], 1);
    csr_s[(size_t)E_N + p] = make_int2(d1g[e], __float_as_int(val1[e]));
  }
  k = d1g[e];
  if (k >= v0 && k < v1) {
    p = atomicAdd(&cursors[3 * V_N + k], 1);
    csr_d[(size_t)E_N + p] = s1g[e];
  }
}

// ---------- W -> bf16 ----------
__global__ __launch_bounds__(256) void k_cvt_W(
    const float* __restrict__ Wsrc, unsigned short* __restrict__ Wdst) {
  size_t i = ((size_t)blockIdx.x * 256 + threadIdx.x) * 8;
  const float4* p = reinterpret_cast<const float4*>(Wsrc + i);
  float4 x0 = p[0], x1 = p[1];
  float xs[8] = {x0.x, x0.y, x0.z, x0.w, x1.x, x1.y, x1.z, x1.w};
  u16x8 o;
  #pragma unroll
  for (int j = 0; j < 8; ++j) o[j] = f2bf_rtn(xs[j]);
  *reinterpret_cast<u16x8*>(Wdst + i) = o;
}

// ---------- Phase 1+2: H gather (payload CSR, 4-wide) + score precompute ----------
__global__ __launch_bounds__(256) void k_gather_H(
    const int* __restrict__ rp, const int2* __restrict__ csr,
    const unsigned short* __restrict__ Wb, const float* __restrict__ a,
    unsigned short* __restrict__ Hb, float* __restrict__ s0, float* __restrict__ s1) {
  int v = blockIdx.x * 4 + (threadIdx.x >> 6);
  if (v >= V_N) return;
  int lane = threadIdx.x & 63;
  int start = rp[v], end = rp[v + 1];
  const u16x4* W4 = reinterpret_cast<const u16x4*>(Wb);
  float4 acc = {0.f, 0.f, 0.f, 0.f};
  int dcur[4]; float fcur[4];
  #pragma unroll
  for (int q = 0; q < 4; ++q) {
    dcur[q] = 0; fcur[q] = 0.f;
    if (start + q < end) { int2 pl = csr[start + q]; dcur[q] = pl.x; fcur[q] = __int_as_float(pl.y); }
  }
  for (int i = start; i < end; i += 4) {
    int dnxt[4]; float fnxt[4];
    #pragma unroll
    for (int q = 0; q < 4; ++q) {
      dnxt[q] = 0; fnxt[q] = 0.f;
      if (i + 4 + q < end) { int2 pl = csr[i + 4 + q]; dnxt[q] = pl.x; fnxt[q] = __int_as_float(pl.y); }
    }
    u16x4 w0 = W4[(size_t)dcur[0] * 64 + lane];
    u16x4 w1 = W4[(size_t)dcur[1] * 64 + lane];
    u16x4 w2 = W4[(size_t)dcur[2] * 64 + lane];
    u16x4 w3 = W4[(size_t)dcur[3] * 64 + lane];
    acc.x += fcur[0] * bf2f(w0[0]) + fcur[1] * bf2f(w1[0]) + fcur[2] * bf2f(w2[0]) + fcur[3] * bf2f(w3[0]);
    acc.y += fcur[0] * bf2f(w0[1]) + fcur[1] * bf2f(w1[1]) + fcur[2] * bf2f(w2[1]) + fcur[3] * bf2f(w3[1]);
    acc.z += fcur[0] * bf2f(w0[2]) + fcur[1] * bf2f(w1[2]) + fcur[2] * bf2f(w2[2]) + fcur[3] * bf2f(w3[2]);
    acc.w += fcur[0] * bf2f(w0[3]) + fcur[1] * bf2f(w1[3]) + fcur[2] * bf2f(w2[3]) + fcur[3] * bf2f(w3[3]);
    #pragma unroll
    for (int q = 0; q < 4; ++q) { dcur[q] = dnxt[q]; fcur[q] = fnxt[q]; }
  }
  u16x4 hb;
  hb[0] = f2bf_rtn(acc.x); hb[1] = f2bf_rtn(acc.y);
  hb[2] = f2bf_rtn(acc.z); hb[3] = f2bf_rtn(acc.w);
  *(reinterpret_cast<u16x4*>(Hb) + (size_t)v * 64 + lane) = hb;
  int h = lane >> 4, dd = (lane & 15) * 4;
  const float* ah = a + h * (2 * HD);
  float p0 = acc.x * ah[dd] + acc.y * ah[dd + 1] + acc.z * ah[dd + 2] + acc.w * ah[dd + 3];
  float p1 = acc.x * ah[HD + dd] + acc.y * ah[HD + dd + 1] + acc.z * ah[HD + dd + 2] + acc.w * ah[HD + dd + 3];
  #pragma unroll
  for (int off = 1; off < 16; off <<= 1) {
    p0 += __shfl_xor(p0, off);
    p1 += __shfl_xor(p1, off);
  }
  if ((lane & 15) == 0) {
    s0[v * HEADS + h] = p0;
    s1[v * HEADS + h] = p1;
  }
}

// ---------- Phase 3+4: single-pass softmax + aggregation (payload CSR, 4-wide) ----------
__global__ __launch_bounds__(256) void k_fused_agg(
    const int* __restrict__ rp, const int* __restrict__ csr,
    const float* __restrict__ s0, const float* __restrict__ s1,
    const unsigned short* __restrict__ Hb, float* __restrict__ Hsum) {
  int v = blockIdx.x * 4 + (threadIdx.x >> 6);
  if (v >= V_N) return;
  int lane = threadIdx.x & 63;
  int start = rp[v], end = rp[v + 1];
  int hB = lane >> 4;
  float s1B = s1[v * HEADS + hB];
  const u16x4* H4 = reinterpret_cast<const u16x4*>(Hb);
  float4 acc = {0.f, 0.f, 0.f, 0.f};
  float dsum = 0.f;
  int svc[4]; float pc[4];
  #pragma unroll
  for (int q = 0; q < 4; ++q) {
    svc[q] = 0; pc[q] = -1e30f;
    if (start + q < end) { svc[q] = csr[start + q]; pc[q] = s0[svc[q] * HEADS + hB]; }
  }
  for (int i = start; i < end; i += 4) {
    int svn[4]; float pn[4];
    #pragma unroll
    for (int q = 0; q < 4; ++q) {
      svn[q] = 0; pn[q] = -1e30f;
      if (i + 4 + q < end) { svn[q] = csr[i + 4 + q]; pn[q] = s0[svn[q] * HEADS + hB]; }
    }
    u16x4 h0 = H4[(size_t)svc[0] * 64 + lane];
    u16x4 h1 = H4[(size_t)svc[1] * 64 + lane];
    u16x4 h2 = H4[(size_t)svc[2] * 64 + lane];
    u16x4 h3 = H4[(size_t)svc[3] * 64 + lane];
    float ex[4];
    #pragma unroll
    for (int q = 0; q < 4; ++q) {
      float sc = pc[q] + s1B;
      sc = sc > 0.f ? sc : NEG_SLOPE * sc;
      ex[q] = expf(sc);
      dsum += ex[q];
    }
    acc.x += ex[0] * bf2f(h0[0]) + ex[1] * bf2f(h1[0]) + ex[2] * bf2f(h2[0]) + ex[3] * bf2f(h3[0]);
    acc.y += ex[0] * bf2f(h0[1]) + ex[1] * bf2f(h1[1]) + ex[2] * bf2f(h2[1]) + ex[3] * bf2f(h3[1]);
    acc.z += ex[0] * bf2f(h0[2]) + ex[1] * bf2f(h1[2]) + ex[2] * bf2f(h2[2]) + ex[3] * bf2f(h3[2]);
    acc.w += ex[0] * bf2f(h0[3]) + ex[1] * bf2f(h1[3]) + ex[2] * bf2f(h2[3]) + ex[3] * bf2f(h3[3]);
    #pragma unroll
    for (int q = 0; q < 4; ++q) { svc[q] = svn[q]; pc[q] = pn[q]; }
  }
  float inv = 1.f / (dsum + EPS_F);
  float4* o = reinterpret_cast<float4*>(Hsum) + (size_t)v * 64 + lane;
  float4 prev = *o;
  prev.x += acc.x * inv; prev.y += acc.y * inv;
  prev.z += acc.z * inv; prev.w += acc.w * inv;
  *o = prev;
}

// ---------- X -> bf16, granule-XOR-swizzled within each 128B block ----------
__global__ __launch_bounds__(256) void k_cvt_X(
    const float* __restrict__ X, unsigned short* __restrict__ Xhi) {
  int row = blockIdx.y;
  int g = blockIdx.x * 256 + threadIdx.x;
  if (g >= K_PAD / 8) return;
  int k0 = g * 8;
  u16x8 hi;
  if (k0 < K_DIM) {
    const float4* p = reinterpret_cast<const float4*>(X + (size_t)row * K_DIM + k0);
    float4 x0 = p[0], x1 = p[1];
    float xs[8] = {x0.x, x0.y, x0.z, x0.w, x1.x, x1.y, x1.z, x1.w};
    #pragma unroll
    for (int j = 0; j < 8; ++j) hi[j] = f2bf_rtn(xs[j]);
  } else {
    #pragma unroll
    for (int j = 0; j < 8; ++j) hi[j] = 0;
  }
  int gs = (g & ~7) | ((g & 7) ^ (row & 7));
  *reinterpret_cast<u16x8*>(Xhi + (size_t)row * K_PAD + gs * 8) = hi;
}

// ---------- Hsum -> transposed bf16 hi/lo split: Bt[h][k], K padded ----------
__global__ __launch_bounds__(256) void k_cvt_B(
    const float* __restrict__ Hs, unsigned short* __restrict__ Bthi,
    unsigned short* __restrict__ Btlo) {
  __shared__ float tile[64][65];
  const int t = threadIdx.x;
  const int v0 = blockIdx.x * 64;
  const int h0 = blockIdx.y * 64;
  #pragma unroll
  for (int i = 0; i < 16; ++i) {
    int vloc = (t >> 6) + i * 4;
    int v = v0 + vloc;
    float f = (v < V_N) ? Hs[(size_t)v * HID + h0 + (t & 63)] : 0.f;
    tile[vloc][t & 63] = f;
  }
  __syncthreads();
  #pragma unroll
  for (int j = 0; j < 16; ++j) {
    int hloc = (t >> 6) + j * 4;
    int vloc = t & 63;
    float f = tile[vloc][hloc];
    unsigned short h = f2bf_rtn(f);
    unsigned short l = f2bf_rtn(f - bf2f(h));
    size_t o = (size_t)(h0 + hloc) * K_PAD + v0 + vloc;
    Bthi[o] = h;
    Btlo[o] = l;
  }
}

// ---------- Big GEMM: wave-private LDS A staging, no barriers, counted vmcnt ----------
// Each wave owns a 2x4KB LDS double-buffer for its 32 A-rows; partials to `part`
// (plain stores), reduced by k_reduce. XCD-swizzled 752-block grid.
__global__ __launch_bounds__(512, 4) void k_gemm1_mfma(
    const unsigned short* __restrict__ Xhi,
    const unsigned short* __restrict__ Bthi, const unsigned short* __restrict__ Btlo,
    float* __restrict__ part) {
  __shared__ __align__(16) unsigned short Alds[2][8][2048];  // 64 KB
  const int bid = blockIdx.x;
  const int xcd = bid & 7;
  const int slot = bid >> 3;
  const int w = xcd * 94 + slot;       // bijective for 752
  const int zb = w >> 4;               // 0..46 K-chunk
  const int xb = w & 15;               // 0..15 M-block
  const int lane = threadIdx.x & 63;
  const int wave = threadIdx.x >> 6;   // 0..7
  const int mw = wave >> 2;            // 0..1
  const int nw = wave & 3;             // 0..3
  const int m0 = xb * 64;
  const int n0 = nw * 64;
  const int r = lane & 15;
  const int koff = lane >> 4;          // 0..3
  const int kel0 = zb * CHUNK_EL;
  const int xr = r & 7;

  // staging source: instr q covers rows m0+mw*32+q*8+(lane>>3), granule lane&7
  const unsigned short* gsrc =
      Xhi + (size_t)(m0 + mw * 32 + (lane >> 3)) * K_PAD + kel0 + (lane & 7) * 8;
  unsigned short* l0 = &Alds[0][wave][0];
  unsigned short* l1 = &Alds[1][wave][0];

  const unsigned short* Bh[4];
  const unsigned short* Bl[4];
  #pragma unroll
  for (int j = 0; j < 4; ++j) {
    size_t o = (size_t)(n0 + 16 * j + r) * K_PAD + kel0 + koff * 8;
    Bh[j] = Bthi + o;
    Bl[j] = Btlo + o;
  }

  // prologue: stage step 0
  #pragma unroll
  for (int q = 0; q < 4; ++q)
    gload_lds16(gsrc + (size_t)q * 8 * K_PAD, l0 + q * 512);

  f32x4 acc[2][4] = {};
  for (int t = 0; t < NSTEP; ++t) {
    const unsigned short* cur = (t & 1) ? l1 : l0;
    unsigned short* nxt = (t & 1) ? l0 : l1;
    const int toff = t * 64;
    // B loads for kk=0 (issued before next-stage so vmcnt(4) drains them too)
    bf16x8 bh[4], bl[4];
    #pragma unroll
    for (int j = 0; j < 4; ++j) {
      bh[j] = *reinterpret_cast<const bf16x8*>(Bh[j] + toff);
      bl[j] = *reinterpret_cast<const bf16x8*>(Bl[j] + toff);
    }
    // issue next-step staging (stays in flight across this step's MFMAs)
    if (t + 1 < NSTEP) {
      #pragma unroll
      for (int q = 0; q < 4; ++q)
        gload_lds16(gsrc + (t + 1) * 64 + (size_t)q * 8 * K_PAD, nxt + q * 512);
    }
    // wait: drain stage(t) + B(kk=0); leave stage(t+1)'s 4 DMAs outstanding
    asm volatile("s_waitcnt vmcnt(4)" ::: "memory");
    __builtin_amdgcn_sched_barrier(0);
    {
      const int gr = (koff ^ xr) * 8;
      bf16x8 a0 = *reinterpret_cast<const bf16x8*>(cur + r * 64 + gr);
      bf16x8 a1 = *reinterpret_cast<const bf16x8*>(cur + (16 + r) * 64 + gr);
      #pragma unroll
      for (int j = 0; j < 4; ++j) {
        acc[0][j] = __builtin_amdgcn_mfma_f32_16x16x32_bf16(a0, bh[j], acc[0][j], 0, 0, 0);
        acc[1][j] = __builtin_amdgcn_mfma_f32_16x16x32_bf16(a1, bh[j], acc[1][j], 0, 0, 0);
        acc[0][j] = __builtin_amdgcn_mfma_f32_16x16x32_bf16(a0, bl[j], acc[0][j], 0, 0, 0);
        acc[1][j] = __builtin_amdgcn_mfma_f32_16x16x32_bf16(a1, bl[j], acc[1][j], 0, 0, 0);
      }
    }
    // kk=1 (compiler inserts its own counted waits for these B loads)
    #pragma unroll
    for (int j = 0; j < 4; ++j) {
      bh[j] = *reinterpret_cast<const bf16x8*>(Bh[j] + toff + 32);
      bl[j] = *reinterpret_cast<const bf16x8*>(Bl[j] + toff + 32);
    }
    {
      const int gr = ((4 + koff) ^ xr) * 8;
      bf16x8 a0 = *reinterpret_cast<const bf16x8*>(cur + r * 64 + gr);
      bf16x8 a1 = *reinterpret_cast<const bf16x8*>(cur + (16 + r) * 64 + gr);
      #pragma unroll
      for (int j = 0; j < 4; ++j) {
        acc[0][j] = __builtin_amdgcn_mfma_f32_16x16x32_bf16(a0, bh[j], acc[0][j], 0, 0, 0);
        acc[1][j] = __builtin_amdgcn_mfma_f32_16x16x32_bf16(a1, bh[j], acc[1][j], 0, 0, 0);
        acc[0][j] = __builtin_amdgcn_mfma_f32_16x16x32_bf16(a0, bl[j], acc[0][j], 0, 0, 0);
        acc[1][j] = __builtin_amdgcn_mfma_f32_16x16x32_bf16(a1, bl[j], acc[1][j], 0, 0, 0);
      }
    }
  }
  // epilogue: plain stores to this work-id's partial tile [64][256]
  float* pw = part + (size_t)w * (64 * 256);
  #pragma unroll
  for (int i = 0; i < 2; ++i) {
    int rloc = mw * 32 + 16 * i + koff * 4;
    #pragma unroll
    for (int j = 0; j < 4; ++j) {
      int colg = n0 + 16 * j + r;
      #pragma unroll
      for (int jj = 0; jj < 4; ++jj)
        pw[(size_t)(rloc + jj) * 256 + colg] = acc[i][j][jj];
    }
  }
}

// ---------- reduce 47 K-partials -> fused ----------
__global__ __launch_bounds__(256) void k_reduce(
    const float* __restrict__ part, float* __restrict__ fused) {
  const int bd = blockIdx.x;      // 0..1023 = output row
  const int o = threadIdx.x;      // 0..255  = output col
  const int xb = bd >> 6, rl = bd & 63;
  float s = 0.f;
  #pragma unroll 4
  for (int zb = 0; zb < SK_MFMA; ++zb)
    s += part[((size_t)(zb * 16 + xb) * 64 + rl) * 256 + o];
  fused[(size_t)bd * 256 + o] = s;
}

// ---------- out = fused @ fc_w^T + fc_b ----------
__global__ __launch_bounds__(256) void k_gemm2(
    const float* __restrict__ fused, const float* __restrict__ fc_w,
    const float* __restrict__ fc_b, float* __restrict__ out) {
  int bd = blockIdx.x, o = threadIdx.x;
  __shared__ float fs[HID];
  fs[o] = fused[(size_t)bd * HID + o];
  __syncthreads();
  float acc = fc_b[o];
  const float* wr = fc_w + (size_t)o * HID;
  #pragma unroll 8
  for (int h = 0; h < HID; ++h) acc += fs[h] * wr[h];
  out[(size_t)bd * HID + o] = acc;
}

extern "C" void kernel_launch(void* const* d_in, const int* in_sizes, int n_in,
                              void* d_out, int out_size, void* d_ws, size_t ws_size,
                              hipStream_t stream) {
  const float* X    = (const float*)d_in[0];
  const float* W0   = (const float*)d_in[1];
  const float* a0   = (const float*)d_in[2];
  const float* W1   = (const float*)d_in[3];
  const float* a1   = (const float*)d_in[4];
  const float* fc_w = (const float*)d_in[5];
  const float* fc_b = (const float*)d_in[6];
  const float* val0 = (const float*)d_in[7];
  const float* val1 = (const float*)d_in[8];
  const int*   src0 = (const int*)d_in[9];
  const int*   dst0 = (const int*)d_in[10];
  const int*   src1 = (const int*)d_in[11];
  const int*   dst1 = (const int*)d_in[12];
  float* out = (float*)d_out;

  char* ws = (char*)d_ws;
  size_t off = 0;
  auto alloc = [&](size_t bytes) {
    void* p = ws + off;
    off += (bytes + 255) & ~(size_t)255;
    return p;
  };
  int*   deg     = (int*)alloc(4 * (size_t)V_N * 4);
  int*   rowptrs = (int*)alloc(4 * (size_t)(V_N + 1) * 4);
  int*   cursors = (int*)alloc(4 * (size_t)V_N * 4);
  int2*  csr_s   = (int2*)alloc(2 * (size_t)E_N * 8);
  int*   csr_d   = (int*)alloc(2 * (size_t)E_N * 4);     // 3.84 MB
  unsigned short* Hb  = (unsigned short*)alloc((size_t)V_N * HID * 2);  // 15.36 MB
  unsigned short* Wb0 = (unsigned short*)alloc((size_t)V_N * HID * 2);  // 15.36 MB
  unsigned short* Wb1 = (unsigned short*)alloc((size_t)V_N * HID * 2);  // 15.36 MB
  float* Hsum    = (float*)alloc((size_t)V_N * HID * 4);
  float* s0      = (float*)alloc((size_t)V_N * HEADS * 4);
  float* s1      = (float*)alloc((size_t)V_N * HEADS * 4);
  float* fused   = (float*)alloc((size_t)M_ROWS * HID * 4);
  unsigned short* Xhi  = (unsigned short*)alloc((size_t)M_ROWS * K_PAD * 2);
  unsigned short* Bthi = (unsigned short*)alloc((size_t)HID * K_PAD * 2);
  unsigned short* Btlo = (unsigned short*)alloc((size_t)HID * K_PAD * 2);
  // GEMM partials (49.3 MB) alias csr_d..Wb1 (49.9 MB): all four buffers are
  // dead by the time k_gemm1_mfma runs (graph CSR + gathers complete earlier
  // in the same stream).
  float* part = (float*)csr_d;

  hipMemsetAsync(deg, 0, 4 * (size_t)V_N * 4, stream);
  hipMemsetAsync(Hsum, 0, (size_t)V_N * HID * 4, stream);

  const int EB = (E_N + 255) / 256;
  k_hist<<<EB, 256, 0, stream>>>(src0, dst0, src1, dst1, deg);
  k_scan4<<<4, 1024, 0, stream>>>(deg, rowptrs, cursors);
  k_fill<<<dim3(EB, NR), 256, 0, stream>>>(src0, dst0, src1, dst1, val0, val1,
                                           cursors, csr_s, csr_d);

  const int WB = (int)(((size_t)V_N * HID / 8 + 255) / 256);  // 3750
  k_cvt_W<<<WB, 256, 0, stream>>>(W0, Wb0);
  k_cvt_W<<<WB, 256, 0, stream>>>(W1, Wb1);
  k_cvt_X<<<dim3(15, M_ROWS), 256, 0, stream>>>(X, Xhi);

  const int VB = (V_N + 3) / 4;
  for (int g = 0; g < 2; ++g) {
    const unsigned short* Wb = g ? Wb1 : Wb0;
    const float* a  = g ? a1 : a0;
    const int* rp_s = rowptrs + (g * 2 + 0) * (V_N + 1);
    const int* rp_d = rowptrs + (g * 2 + 1) * (V_N + 1);
    const int2* cs  = csr_s + (size_t)g * E_N;
    const int*  cd  = csr_d + (size_t)g * E_N;

    k_gather_H<<<VB, 256, 0, stream>>>(rp_s, cs, Wb, a, Hb, s0, s1);
    k_fused_agg<<<VB, 256, 0, stream>>>(rp_d, cd, s0, s1, Hb, Hsum);
  }

  k_cvt_B<<<dim3(K_PAD / 64, HID / 64), 256, 0, stream>>>(Hsum, Bthi, Btlo);
  k_gemm1_mfma<<<8 * 94, 512, 0, stream>>>(Xhi, Bthi, Btlo, part);
  k_reduce<<<M_ROWS, 256, 0, stream>>>(part, fused);
  k_gemm2<<<M_ROWS, 256, 0, stream>>>(fused, fc_w, fc_b, out);
}